// Round 1
// baseline (7198.669 us; speedup 1.0000x reference)
//
#include <hip/hip_runtime.h>
#include <hip/hip_bf16.h>
#include <math.h>

// Problem constants
#define BATCH 512
#define NSEG  64
#define HID   1024
#define ATT   128

// ---------------------------------------------------------------------------
// Fused conv5x5(same) + maxpool2 + relu.
// One thread per pooled output element. Computes the 4 conv outputs feeding
// its pool window from a register-cached 6x6 input patch per channel.
// ---------------------------------------------------------------------------
template<int Ci, int Co, int Hin>
__global__ __launch_bounds__(256) void conv_pool_relu_k(
    const float* __restrict__ in, const float* __restrict__ w,
    const float* __restrict__ bias, float* __restrict__ out) {
    constexpr int Hout = Hin / 2;
    constexpr int total = BATCH * Co * Hout * Hout;
    int idx = blockIdx.x * 256 + threadIdx.x;
    if (idx >= total) return;

    int x = idx & (Hout - 1);
    int t = idx / Hout;
    int y = t & (Hout - 1);
    t /= Hout;
    int co = t % Co;
    int b  = t / Co;

    float acc00 = 0.f, acc01 = 0.f, acc10 = 0.f, acc11 = 0.f;
    const float* wbase = w + co * (Ci * 25);
    const float* ibase = in + (size_t)b * Ci * Hin * Hin;
    int iy0 = 2 * y - 2;
    int ix0 = 2 * x - 2;

    for (int ci = 0; ci < Ci; ++ci) {
        const float* ip = ibase + ci * Hin * Hin;
        float r[6][6];
#pragma unroll
        for (int dy = 0; dy < 6; ++dy) {
            int iy = iy0 + dy;
            bool okY = (unsigned)iy < (unsigned)Hin;
#pragma unroll
            for (int dx = 0; dx < 6; ++dx) {
                int ix = ix0 + dx;
                bool ok = okY && ((unsigned)ix < (unsigned)Hin);
                r[dy][dx] = ok ? ip[iy * Hin + ix] : 0.f;
            }
        }
        const float* wp = wbase + ci * 25;
#pragma unroll
        for (int kh = 0; kh < 5; ++kh) {
#pragma unroll
            for (int kw = 0; kw < 5; ++kw) {
                float wv = wp[kh * 5 + kw];  // wave-uniform address -> broadcast
                acc00 = fmaf(r[kh][kw],         wv, acc00);
                acc01 = fmaf(r[kh][kw + 1],     wv, acc01);
                acc10 = fmaf(r[kh + 1][kw],     wv, acc10);
                acc11 = fmaf(r[kh + 1][kw + 1], wv, acc11);
            }
        }
    }
    float m = fmaxf(fmaxf(acc00, acc01), fmaxf(acc10, acc11)) + bias[co];
    out[idx] = fmaxf(m, 0.f);
}

// ---------------------------------------------------------------------------
// FC: emb[b][o] = sum_k flat[b][k] * fc_w[o][k] + fc_b[o]
// flat: (512, 2048), fc_w: (1024, 2048). Block: 256 threads, 4 batch rows
// staged in LDS (32 KiB); each thread computes one output column for 4 rows.
// grid = (1024/256, 512/4) = (4, 128)
// ---------------------------------------------------------------------------
__global__ __launch_bounds__(256) void fc_k(
    const float* __restrict__ flat, const float* __restrict__ w,
    const float* __restrict__ bias, float* __restrict__ out) {
    const int t = threadIdx.x;
    const int o = blockIdx.x * 256 + t;
    const int b0 = blockIdx.y * 4;
    __shared__ float a[4 * 2048];
    const float* src = flat + (size_t)b0 * 2048;
    for (int i = t * 4; i < 4 * 2048; i += 256 * 4)
        *(float4*)(a + i) = *(const float4*)(src + i);
    __syncthreads();

    float acc0 = 0.f, acc1 = 0.f, acc2 = 0.f, acc3 = 0.f;
    const float* wr = w + (size_t)o * 2048;
    for (int k = 0; k < 2048; k += 4) {
        float4 wv = *(const float4*)(wr + k);
        float4 a0 = *(const float4*)(a + 0 * 2048 + k);
        float4 a1 = *(const float4*)(a + 1 * 2048 + k);
        float4 a2 = *(const float4*)(a + 2 * 2048 + k);
        float4 a3 = *(const float4*)(a + 3 * 2048 + k);
        acc0 += wv.x * a0.x + wv.y * a0.y + wv.z * a0.z + wv.w * a0.w;
        acc1 += wv.x * a1.x + wv.y * a1.y + wv.z * a1.z + wv.w * a1.w;
        acc2 += wv.x * a2.x + wv.y * a2.y + wv.z * a2.z + wv.w * a2.w;
        acc3 += wv.x * a3.x + wv.y * a3.y + wv.z * a3.z + wv.w * a3.w;
    }
    float bv = bias[o];
    out[(size_t)(b0 + 0) * 1024 + o] = acc0 + bv;
    out[(size_t)(b0 + 1) * 1024 + o] = acc1 + bv;
    out[(size_t)(b0 + 2) * 1024 + o] = acc2 + bv;
    out[(size_t)(b0 + 3) * 1024 + o] = acc3 + bv;
}

// ---------------------------------------------------------------------------
// Attention: logits[b] = sum_j tanh(emb[b] . att_w1[j] + b1[j]) * att_w2[j] + b2
// One block (128 threads) per instance b.
// ---------------------------------------------------------------------------
__global__ __launch_bounds__(128) void attention_k(
    const float* __restrict__ emb, const float* __restrict__ w1,
    const float* __restrict__ b1, const float* __restrict__ w2,
    const float* __restrict__ b2, float* __restrict__ logits) {
    const int b = blockIdx.x;
    const int j = threadIdx.x;
    __shared__ float es[HID];
    for (int k = j; k < HID; k += 128) es[k] = emb[(size_t)b * HID + k];
    __syncthreads();

    float s = b1[j];
    const float* wr = w1 + (size_t)j * HID;
    for (int k = 0; k < HID; k += 4) {
        float4 wv = *(const float4*)(wr + k);
        float4 ev = *(const float4*)(es + k);
        s += wv.x * ev.x + wv.y * ev.y + wv.z * ev.z + wv.w * ev.w;
    }
    float v = tanhf(s) * w2[j];
#pragma unroll
    for (int off = 32; off > 0; off >>= 1) v += __shfl_down(v, off);
    __shared__ float wsum[2];
    if ((j & 63) == 0) wsum[j >> 6] = v;
    __syncthreads();
    if (j == 0) logits[b] = wsum[0] + wsum[1] + b2[0];
}

// ---------------------------------------------------------------------------
// Segment softmax + weighted aggregation + classifier, fused.
// One block (256 threads) per segment. case_ids membership branch is
// block-uniform (no divergence). Empty segments -> aggr = 0.
// ---------------------------------------------------------------------------
__global__ __launch_bounds__(256) void segment_k(
    const float* __restrict__ emb, const float* __restrict__ logits,
    const int* __restrict__ cid, const float* __restrict__ clf_w,
    const float* __restrict__ clf_b, float* __restrict__ out) {
    const int c = blockIdx.x;
    const int t = threadIdx.x;
    __shared__ int cids[BATCH];
    __shared__ float red[256];
    for (int i = t; i < BATCH; i += 256) cids[i] = cid[i];
    __syncthreads();

    // segment max
    float lm = -1e30f;
    for (int b = t; b < BATCH; b += 256)
        if (cids[b] == c) lm = fmaxf(lm, logits[b]);
    red[t] = lm; __syncthreads();
    for (int s = 128; s > 0; s >>= 1) {
        if (t < s) red[t] = fmaxf(red[t], red[t + s]);
        __syncthreads();
    }
    float smax = red[0]; __syncthreads();

    // segment sum of exp
    float ls = 0.f;
    for (int b = t; b < BATCH; b += 256)
        if (cids[b] == c) ls += expf(logits[b] - smax);
    red[t] = ls; __syncthreads();
    for (int s = 128; s > 0; s >>= 1) {
        if (t < s) red[t] += red[t + s];
        __syncthreads();
    }
    float denom = red[0]; __syncthreads();
    float inv = (denom > 0.f) ? 1.f / denom : 0.f;

    // weighted aggregation of emb (each thread owns 4 hidden dims) + clf dot
    const int h0 = t * 4;
    float g0 = 0.f, g1 = 0.f, g2 = 0.f, g3 = 0.f;
    for (int b = 0; b < BATCH; ++b) {
        if (cids[b] == c) {  // uniform branch
            float wgt = expf(logits[b] - smax) * inv;
            float4 ev = *(const float4*)(emb + (size_t)b * HID + h0);
            g0 = fmaf(wgt, ev.x, g0);
            g1 = fmaf(wgt, ev.y, g1);
            g2 = fmaf(wgt, ev.z, g2);
            g3 = fmaf(wgt, ev.w, g3);
        }
    }
    float4 cw = *(const float4*)(clf_w + h0);
    float ca = g0 * cw.x + g1 * cw.y + g2 * cw.z + g3 * cw.w;
    red[t] = ca; __syncthreads();
    for (int s = 128; s > 0; s >>= 1) {
        if (t < s) red[t] += red[t + s];
        __syncthreads();
    }
    if (t == 0) out[c] = 1.f / (1.f + expf(-(red[0] + clf_b[0])));
}

// ---------------------------------------------------------------------------
extern "C" void kernel_launch(void* const* d_in, const int* in_sizes, int n_in,
                              void* d_out, int out_size, void* d_ws, size_t ws_size,
                              hipStream_t stream) {
    const float* data = (const float*)d_in[0];
    const int*   cid  = (const int*)d_in[1];
    const float* cw1 = (const float*)d_in[2],  * cb1 = (const float*)d_in[3];
    const float* cw2 = (const float*)d_in[4],  * cb2 = (const float*)d_in[5];
    const float* cw3 = (const float*)d_in[6],  * cb3 = (const float*)d_in[7];
    const float* cw4 = (const float*)d_in[8],  * cb4 = (const float*)d_in[9];
    const float* cw5 = (const float*)d_in[10], * cb5 = (const float*)d_in[11];
    const float* fcw = (const float*)d_in[12], * fcb = (const float*)d_in[13];
    const float* aw1 = (const float*)d_in[14], * ab1 = (const float*)d_in[15];
    const float* aw2 = (const float*)d_in[16], * ab2 = (const float*)d_in[17];
    const float* clw = (const float*)d_in[18], * clb = (const float*)d_in[19];
    float* out = (float*)d_out;

    // workspace layout (floats), ping-pong reuse; peak = 25,165,824 floats
    float* ws = (float*)d_ws;
    float* x1  = ws;                    // 512* 8*64*64 = 16,777,216  @ 0
    float* x2  = ws + 16777216;         // 512*16*32*32 =  8,388,608  @ 16M
    float* x3  = ws;                    // 512*32*16*16 =  4,194,304  reuse of x1
    float* x4  = ws + 16777216;         // 512*64* 8* 8 =  2,097,152  reuse of x2
    float* x5  = ws;                    // 512*128*4*4  =  1,048,576  reuse of x3
    float* emb = ws + 16777216;         // 512*1024     =    524,288  reuse of x4
    float* lg  = ws + 16777216 + 524288;// 512

    conv_pool_relu_k<3, 8, 128><<<(BATCH *   8 * 64 * 64) / 256, 256, 0, stream>>>(data, cw1, cb1, x1);
    conv_pool_relu_k<8, 16, 64><<<(BATCH *  16 * 32 * 32) / 256, 256, 0, stream>>>(x1,   cw2, cb2, x2);
    conv_pool_relu_k<16, 32, 32><<<(BATCH * 32 * 16 * 16) / 256, 256, 0, stream>>>(x2,   cw3, cb3, x3);
    conv_pool_relu_k<32, 64, 16><<<(BATCH * 64 *  8 *  8) / 256, 256, 0, stream>>>(x3,   cw4, cb4, x4);
    conv_pool_relu_k<64, 128, 8><<<(BATCH * 128 * 4 *  4) / 256, 256, 0, stream>>>(x4,   cw5, cb5, x5);

    fc_k<<<dim3(HID / 256, BATCH / 4), 256, 0, stream>>>(x5, fcw, fcb, emb);
    attention_k<<<BATCH, 128, 0, stream>>>(emb, aw1, ab1, aw2, ab2, lg);
    segment_k<<<NSEG, 256, 0, stream>>>(emb, lg, cid, clw, clb, out);
}

// Round 2
// 1488.941 us; speedup vs baseline: 4.8348x; 4.8348x over previous
//
#include <hip/hip_runtime.h>
#include <hip/hip_bf16.h>
#include <math.h>

// Problem constants
#define BATCH 512
#define NSEG  64
#define HID   1024
#define ATT   128

// ---------------------------------------------------------------------------
// Fused conv5x5(same) + maxpool2 + relu, output-channel-chunked.
// One thread = one pooled output pixel for CC consecutive output channels.
// blockIdx.y selects the co-chunk so weight/bias addresses are wave-uniform
// (scalar loads). Per input channel: 36 predicated patch loads reused for
// CC*100 FMAs.
// grid = (BATCH*PIX/256, Co/CC)
// ---------------------------------------------------------------------------
template<int Ci, int Co, int CC, int Hin>
__global__ __launch_bounds__(256) void conv_pool_relu_k(
    const float* __restrict__ in, const float* __restrict__ w,
    const float* __restrict__ bias, float* __restrict__ out) {
    constexpr int Hout = Hin / 2;
    constexpr int PIX = Hout * Hout;

    const int tid = blockIdx.x * 256 + threadIdx.x;
    const int pix = tid & (PIX - 1);
    const int b   = tid / PIX;
    const int x   = pix & (Hout - 1);
    const int y   = pix / Hout;
    const int co0 = blockIdx.y * CC;   // block-uniform

    const float* __restrict__ wbase = w + (size_t)co0 * (Ci * 25);  // uniform
    const float* __restrict__ ibase = in + (size_t)b * Ci * Hin * Hin;

    const int iy0 = 2 * y - 2;
    const int ix0 = 2 * x - 2;

    // Hoisted validity masks and offsets for the 6x6 patch
    bool okY[6], okX[6];
    int offY[6], offX[6];
#pragma unroll
    for (int d = 0; d < 6; ++d) {
        int iy = iy0 + d;
        okY[d] = (unsigned)iy < (unsigned)Hin;
        offY[d] = okY[d] ? iy * Hin : 0;
        int ix = ix0 + d;
        okX[d] = (unsigned)ix < (unsigned)Hin;
        offX[d] = okX[d] ? ix : 0;
    }

    float acc[CC * 4];
#pragma unroll
    for (int i = 0; i < CC * 4; ++i) acc[i] = 0.f;

    for (int ci = 0; ci < Ci; ++ci) {
        const float* __restrict__ ip = ibase + ci * Hin * Hin;
        float r[36];
#pragma unroll
        for (int dy = 0; dy < 6; ++dy) {
#pragma unroll
            for (int dx = 0; dx < 6; ++dx) {
                bool ok = okY[dy] && okX[dx];
                r[dy * 6 + dx] = ok ? ip[offY[dy] + offX[dx]] : 0.f;
            }
        }
#pragma unroll
        for (int cc = 0; cc < CC; ++cc) {
            const float* __restrict__ wp = wbase + cc * (Ci * 25) + ci * 25;  // uniform
#pragma unroll
            for (int kh = 0; kh < 5; ++kh) {
#pragma unroll
                for (int kw = 0; kw < 5; ++kw) {
                    float wv = wp[kh * 5 + kw];  // scalar (uniform) load
                    acc[cc * 4 + 0] = fmaf(r[kh * 6 + kw],           wv, acc[cc * 4 + 0]);
                    acc[cc * 4 + 1] = fmaf(r[kh * 6 + kw + 1],       wv, acc[cc * 4 + 1]);
                    acc[cc * 4 + 2] = fmaf(r[(kh + 1) * 6 + kw],     wv, acc[cc * 4 + 2]);
                    acc[cc * 4 + 3] = fmaf(r[(kh + 1) * 6 + kw + 1], wv, acc[cc * 4 + 3]);
                }
            }
        }
    }

#pragma unroll
    for (int cc = 0; cc < CC; ++cc) {
        float m = fmaxf(fmaxf(acc[cc * 4 + 0], acc[cc * 4 + 1]),
                        fmaxf(acc[cc * 4 + 2], acc[cc * 4 + 3])) + bias[co0 + cc];
        out[((size_t)b * Co + co0 + cc) * PIX + pix] = fmaxf(m, 0.f);
    }
}

// ---------------------------------------------------------------------------
// FC: emb[b][o] = sum_k flat[b][k] * fc_w[o][k] + fc_b[o]
// ---------------------------------------------------------------------------
__global__ __launch_bounds__(256) void fc_k(
    const float* __restrict__ flat, const float* __restrict__ w,
    const float* __restrict__ bias, float* __restrict__ out) {
    const int t = threadIdx.x;
    const int o = blockIdx.x * 256 + t;
    const int b0 = blockIdx.y * 4;
    __shared__ float a[4 * 2048];
    const float* src = flat + (size_t)b0 * 2048;
    for (int i = t * 4; i < 4 * 2048; i += 256 * 4)
        *(float4*)(a + i) = *(const float4*)(src + i);
    __syncthreads();

    float acc0 = 0.f, acc1 = 0.f, acc2 = 0.f, acc3 = 0.f;
    const float* wr = w + (size_t)o * 2048;
    for (int k = 0; k < 2048; k += 4) {
        float4 wv = *(const float4*)(wr + k);
        float4 a0 = *(const float4*)(a + 0 * 2048 + k);
        float4 a1 = *(const float4*)(a + 1 * 2048 + k);
        float4 a2 = *(const float4*)(a + 2 * 2048 + k);
        float4 a3 = *(const float4*)(a + 3 * 2048 + k);
        acc0 += wv.x * a0.x + wv.y * a0.y + wv.z * a0.z + wv.w * a0.w;
        acc1 += wv.x * a1.x + wv.y * a1.y + wv.z * a1.z + wv.w * a1.w;
        acc2 += wv.x * a2.x + wv.y * a2.y + wv.z * a2.z + wv.w * a2.w;
        acc3 += wv.x * a3.x + wv.y * a3.y + wv.z * a3.z + wv.w * a3.w;
    }
    float bv = bias[o];
    out[(size_t)(b0 + 0) * 1024 + o] = acc0 + bv;
    out[(size_t)(b0 + 1) * 1024 + o] = acc1 + bv;
    out[(size_t)(b0 + 2) * 1024 + o] = acc2 + bv;
    out[(size_t)(b0 + 3) * 1024 + o] = acc3 + bv;
}

// ---------------------------------------------------------------------------
// Attention: logits[b] = sum_j tanh(emb[b] . att_w1[j] + b1[j]) * att_w2[j] + b2
// ---------------------------------------------------------------------------
__global__ __launch_bounds__(128) void attention_k(
    const float* __restrict__ emb, const float* __restrict__ w1,
    const float* __restrict__ b1, const float* __restrict__ w2,
    const float* __restrict__ b2, float* __restrict__ logits) {
    const int b = blockIdx.x;
    const int j = threadIdx.x;
    __shared__ float es[HID];
    for (int k = j; k < HID; k += 128) es[k] = emb[(size_t)b * HID + k];
    __syncthreads();

    float s = b1[j];
    const float* wr = w1 + (size_t)j * HID;
    for (int k = 0; k < HID; k += 4) {
        float4 wv = *(const float4*)(wr + k);
        float4 ev = *(const float4*)(es + k);
        s += wv.x * ev.x + wv.y * ev.y + wv.z * ev.z + wv.w * ev.w;
    }
    float v = tanhf(s) * w2[j];
#pragma unroll
    for (int off = 32; off > 0; off >>= 1) v += __shfl_down(v, off);
    __shared__ float wsum[2];
    if ((j & 63) == 0) wsum[j >> 6] = v;
    __syncthreads();
    if (j == 0) logits[b] = wsum[0] + wsum[1] + b2[0];
}

// ---------------------------------------------------------------------------
// Segment softmax + weighted aggregation + classifier, fused.
// ---------------------------------------------------------------------------
__global__ __launch_bounds__(256) void segment_k(
    const float* __restrict__ emb, const float* __restrict__ logits,
    const int* __restrict__ cid, const float* __restrict__ clf_w,
    const float* __restrict__ clf_b, float* __restrict__ out) {
    const int c = blockIdx.x;
    const int t = threadIdx.x;
    __shared__ int cids[BATCH];
    __shared__ float red[256];
    for (int i = t; i < BATCH; i += 256) cids[i] = cid[i];
    __syncthreads();

    float lm = -1e30f;
    for (int b = t; b < BATCH; b += 256)
        if (cids[b] == c) lm = fmaxf(lm, logits[b]);
    red[t] = lm; __syncthreads();
    for (int s = 128; s > 0; s >>= 1) {
        if (t < s) red[t] = fmaxf(red[t], red[t + s]);
        __syncthreads();
    }
    float smax = red[0]; __syncthreads();

    float ls = 0.f;
    for (int b = t; b < BATCH; b += 256)
        if (cids[b] == c) ls += expf(logits[b] - smax);
    red[t] = ls; __syncthreads();
    for (int s = 128; s > 0; s >>= 1) {
        if (t < s) red[t] += red[t + s];
        __syncthreads();
    }
    float denom = red[0]; __syncthreads();
    float inv = (denom > 0.f) ? 1.f / denom : 0.f;

    const int h0 = t * 4;
    float g0 = 0.f, g1 = 0.f, g2 = 0.f, g3 = 0.f;
    for (int b = 0; b < BATCH; ++b) {
        if (cids[b] == c) {  // uniform branch
            float wgt = expf(logits[b] - smax) * inv;
            float4 ev = *(const float4*)(emb + (size_t)b * HID + h0);
            g0 = fmaf(wgt, ev.x, g0);
            g1 = fmaf(wgt, ev.y, g1);
            g2 = fmaf(wgt, ev.z, g2);
            g3 = fmaf(wgt, ev.w, g3);
        }
    }
    float4 cw = *(const float4*)(clf_w + h0);
    float ca = g0 * cw.x + g1 * cw.y + g2 * cw.z + g3 * cw.w;
    red[t] = ca; __syncthreads();
    for (int s = 128; s > 0; s >>= 1) {
        if (t < s) red[t] += red[t + s];
        __syncthreads();
    }
    if (t == 0) out[c] = 1.f / (1.f + expf(-(red[0] + clf_b[0])));
}

// ---------------------------------------------------------------------------
extern "C" void kernel_launch(void* const* d_in, const int* in_sizes, int n_in,
                              void* d_out, int out_size, void* d_ws, size_t ws_size,
                              hipStream_t stream) {
    const float* data = (const float*)d_in[0];
    const int*   cid  = (const int*)d_in[1];
    const float* cw1 = (const float*)d_in[2],  * cb1 = (const float*)d_in[3];
    const float* cw2 = (const float*)d_in[4],  * cb2 = (const float*)d_in[5];
    const float* cw3 = (const float*)d_in[6],  * cb3 = (const float*)d_in[7];
    const float* cw4 = (const float*)d_in[8],  * cb4 = (const float*)d_in[9];
    const float* cw5 = (const float*)d_in[10], * cb5 = (const float*)d_in[11];
    const float* fcw = (const float*)d_in[12], * fcb = (const float*)d_in[13];
    const float* aw1 = (const float*)d_in[14], * ab1 = (const float*)d_in[15];
    const float* aw2 = (const float*)d_in[16], * ab2 = (const float*)d_in[17];
    const float* clw = (const float*)d_in[18], * clb = (const float*)d_in[19];
    float* out = (float*)d_out;

    // workspace layout (floats), ping-pong reuse
    float* ws = (float*)d_ws;
    float* x1  = ws;                     // 512* 8*64*64 = 16,777,216
    float* x2  = ws + 16777216;          // 512*16*32*32 =  8,388,608
    float* x3  = ws;                     // reuse
    float* x4  = ws + 16777216;          // reuse
    float* x5  = ws;                     // reuse
    float* emb = ws + 16777216;          // 512*1024
    float* lg  = ws + 16777216 + 524288; // 512

    // grid = (BATCH*PIX/256, Co/CC)
    conv_pool_relu_k<3,   8,  8, 128><<<dim3(512 * 4096 / 256, 1),  256, 0, stream>>>(data, cw1, cb1, x1);
    conv_pool_relu_k<8,  16, 16,  64><<<dim3(512 * 1024 / 256, 1),  256, 0, stream>>>(x1,   cw2, cb2, x2);
    conv_pool_relu_k<16, 32, 16,  32><<<dim3(512 *  256 / 256, 2),  256, 0, stream>>>(x2,   cw3, cb3, x3);
    conv_pool_relu_k<32, 64, 16,  16><<<dim3(512 *   64 / 256, 4),  256, 0, stream>>>(x3,   cw4, cb4, x4);
    conv_pool_relu_k<64, 128, 8,   8><<<dim3(512 *   16 / 256, 16), 256, 0, stream>>>(x4,   cw5, cb5, x5);

    fc_k<<<dim3(HID / 256, BATCH / 4), 256, 0, stream>>>(x5, fcw, fcb, emb);
    attention_k<<<BATCH, 128, 0, stream>>>(emb, aw1, ab1, aw2, ab2, lg);
    segment_k<<<NSEG, 256, 0, stream>>>(emb, lg, cid, clw, clb, out);
}

// Round 4
// 1288.838 us; speedup vs baseline: 5.5854x; 1.1553x over previous
//
#include <hip/hip_runtime.h>
#include <hip/hip_bf16.h>
#include <math.h>

// Problem constants
#define BATCH 512
#define NSEG  64
#define HID   1024
#define ATT   128

// ---------------------------------------------------------------------------
// Fused conv5x5(same) + maxpool2 + relu, output-channel-chunked.
// One thread = one pooled output pixel for CC consecutive output channels.
// blockIdx.y selects the co-chunk (wave-uniform weight addresses -> s_load).
// Patch rows loaded as 3x float2: ix0 = 2x-2 is even. dx=2,3 (ix=2x,2x+1)
// are ALWAYS in-range in x; dx=0,1 need x>=1 (left edge); dx=4,5 need
// x<Hout-1 (right edge). Invalid lanes use a clamped-safe address (offset 0)
// and are value-masked to zero. Per ci: 18 vector loads reused for CC*100
// FMAs. CC per layer keeps >=4 waves/SIMD: conv1-3 CC=8, conv4-5 CC=4.
// grid = (BATCH*PIX/256, Co/CC)
// ---------------------------------------------------------------------------
template<int Ci, int Co, int CC, int Hin>
__global__ __launch_bounds__(256) void conv_pool_relu_k(
    const float* __restrict__ in, const float* __restrict__ w,
    const float* __restrict__ bias, float* __restrict__ out) {
    constexpr int Hout = Hin / 2;
    constexpr int PIX = Hout * Hout;

    const int tid = blockIdx.x * 256 + threadIdx.x;
    const int pix = tid & (PIX - 1);
    const int b   = tid / PIX;
    const int x   = pix & (Hout - 1);
    const int y   = pix / Hout;
    const int co0 = blockIdx.y * CC;   // block-uniform

    const float* __restrict__ wbase = w + (size_t)co0 * (Ci * 25);  // uniform
    const float* __restrict__ ibase = in + (size_t)b * Ci * Hin * Hin;

    const int iy0 = 2 * y - 2;
    const int ix0 = 2 * x - 2;
    const bool xL = (x >= 1);         // left pair  (dx=0,1) valid iff x>=1
    const bool xR = (x < Hout - 1);   // right pair (dx=4,5) valid iff x<Hout-1

    // Hoisted per-row validity and safe base offsets
    bool vy[6];
    int rb[6];
#pragma unroll
    for (int d = 0; d < 6; ++d) {
        int iy = iy0 + d;
        vy[d] = (unsigned)iy < (unsigned)Hin;
        rb[d] = vy[d] ? iy * Hin : 0;
    }

    float acc[CC * 4];
#pragma unroll
    for (int i = 0; i < CC * 4; ++i) acc[i] = 0.f;

    for (int ci = 0; ci < Ci; ++ci) {
        const float* __restrict__ ip = ibase + ci * Hin * Hin;
        float r[36];
#pragma unroll
        for (int dy = 0; dy < 6; ++dy) {
            bool vA = vy[dy] && xL;
            bool vC = vy[dy] && xR;
            // clamped addresses are always legal (offset 0 fallback)
            float2 pA = *(const float2*)(ip + (vA ? rb[dy] + ix0 : 0));
            float2 pB = *(const float2*)(ip + rb[dy] + ix0 + 2);        // ix=2x,2x+1: always in-range
            float2 pC = *(const float2*)(ip + (vC ? rb[dy] + ix0 + 4 : 0));
            r[dy * 6 + 0] = vA ? pA.x : 0.f;
            r[dy * 6 + 1] = vA ? pA.y : 0.f;
            r[dy * 6 + 2] = vy[dy] ? pB.x : 0.f;
            r[dy * 6 + 3] = vy[dy] ? pB.y : 0.f;
            r[dy * 6 + 4] = vC ? pC.x : 0.f;
            r[dy * 6 + 5] = vC ? pC.y : 0.f;
        }
#pragma unroll
        for (int cc = 0; cc < CC; ++cc) {
            const float* __restrict__ wp = wbase + cc * (Ci * 25) + ci * 25;  // uniform
#pragma unroll
            for (int kh = 0; kh < 5; ++kh) {
#pragma unroll
                for (int kw = 0; kw < 5; ++kw) {
                    float wv = wp[kh * 5 + kw];  // scalar (uniform) load
                    acc[cc * 4 + 0] = fmaf(r[kh * 6 + kw],           wv, acc[cc * 4 + 0]);
                    acc[cc * 4 + 1] = fmaf(r[kh * 6 + kw + 1],       wv, acc[cc * 4 + 1]);
                    acc[cc * 4 + 2] = fmaf(r[(kh + 1) * 6 + kw],     wv, acc[cc * 4 + 2]);
                    acc[cc * 4 + 3] = fmaf(r[(kh + 1) * 6 + kw + 1], wv, acc[cc * 4 + 3]);
                }
            }
        }
    }

#pragma unroll
    for (int cc = 0; cc < CC; ++cc) {
        float m = fmaxf(fmaxf(acc[cc * 4 + 0], acc[cc * 4 + 1]),
                        fmaxf(acc[cc * 4 + 2], acc[cc * 4 + 3])) + bias[co0 + cc];
        out[((size_t)b * Co + co0 + cc) * PIX + pix] = fmaxf(m, 0.f);
    }
}

// ---------------------------------------------------------------------------
// FC: emb[b][o] = sum_k flat[b][k] * fc_w[o][k] + fc_b[o]
// ---------------------------------------------------------------------------
__global__ __launch_bounds__(256) void fc_k(
    const float* __restrict__ flat, const float* __restrict__ w,
    const float* __restrict__ bias, float* __restrict__ out) {
    const int t = threadIdx.x;
    const int o = blockIdx.x * 256 + t;
    const int b0 = blockIdx.y * 4;
    __shared__ float a[4 * 2048];
    const float* src = flat + (size_t)b0 * 2048;
    for (int i = t * 4; i < 4 * 2048; i += 256 * 4)
        *(float4*)(a + i) = *(const float4*)(src + i);
    __syncthreads();

    float acc0 = 0.f, acc1 = 0.f, acc2 = 0.f, acc3 = 0.f;
    const float* wr = w + (size_t)o * 2048;
    for (int k = 0; k < 2048; k += 4) {
        float4 wv = *(const float4*)(wr + k);
        float4 a0 = *(const float4*)(a + 0 * 2048 + k);
        float4 a1 = *(const float4*)(a + 1 * 2048 + k);
        float4 a2 = *(const float4*)(a + 2 * 2048 + k);
        float4 a3 = *(const float4*)(a + 3 * 2048 + k);
        acc0 += wv.x * a0.x + wv.y * a0.y + wv.z * a0.z + wv.w * a0.w;
        acc1 += wv.x * a1.x + wv.y * a1.y + wv.z * a1.z + wv.w * a1.w;
        acc2 += wv.x * a2.x + wv.y * a2.y + wv.z * a2.z + wv.w * a2.w;
        acc3 += wv.x * a3.x + wv.y * a3.y + wv.z * a3.z + wv.w * a3.w;
    }
    float bv = bias[o];
    out[(size_t)(b0 + 0) * 1024 + o] = acc0 + bv;
    out[(size_t)(b0 + 1) * 1024 + o] = acc1 + bv;
    out[(size_t)(b0 + 2) * 1024 + o] = acc2 + bv;
    out[(size_t)(b0 + 3) * 1024 + o] = acc3 + bv;
}

// ---------------------------------------------------------------------------
// Attention: logits[b] = sum_j tanh(emb[b] . att_w1[j] + b1[j]) * att_w2[j] + b2
// ---------------------------------------------------------------------------
__global__ __launch_bounds__(128) void attention_k(
    const float* __restrict__ emb, const float* __restrict__ w1,
    const float* __restrict__ b1, const float* __restrict__ w2,
    const float* __restrict__ b2, float* __restrict__ logits) {
    const int b = blockIdx.x;
    const int j = threadIdx.x;
    __shared__ float es[HID];
    for (int k = j; k < HID; k += 128) es[k] = emb[(size_t)b * HID + k];
    __syncthreads();

    float s = b1[j];
    const float* wr = w1 + (size_t)j * HID;
    for (int k = 0; k < HID; k += 4) {
        float4 wv = *(const float4*)(wr + k);
        float4 ev = *(const float4*)(es + k);
        s += wv.x * ev.x + wv.y * ev.y + wv.z * ev.z + wv.w * ev.w;
    }
    float v = tanhf(s) * w2[j];
#pragma unroll
    for (int off = 32; off > 0; off >>= 1) v += __shfl_down(v, off);
    __shared__ float wsum[2];
    if ((j & 63) == 0) wsum[j >> 6] = v;
    __syncthreads();
    if (j == 0) logits[b] = wsum[0] + wsum[1] + b2[0];
}

// ---------------------------------------------------------------------------
// Segment softmax + weighted aggregation + classifier, fused.
// ---------------------------------------------------------------------------
__global__ __launch_bounds__(256) void segment_k(
    const float* __restrict__ emb, const float* __restrict__ logits,
    const int* __restrict__ cid, const float* __restrict__ clf_w,
    const float* __restrict__ clf_b, float* __restrict__ out) {
    const int c = blockIdx.x;
    const int t = threadIdx.x;
    __shared__ int cids[BATCH];
    __shared__ float red[256];
    for (int i = t; i < BATCH; i += 256) cids[i] = cid[i];
    __syncthreads();

    float lm = -1e30f;
    for (int b = t; b < BATCH; b += 256)
        if (cids[b] == c) lm = fmaxf(lm, logits[b]);
    red[t] = lm; __syncthreads();
    for (int s = 128; s > 0; s >>= 1) {
        if (t < s) red[t] = fmaxf(red[t], red[t + s]);
        __syncthreads();
    }
    float smax = red[0]; __syncthreads();

    float ls = 0.f;
    for (int b = t; b < BATCH; b += 256)
        if (cids[b] == c) ls += expf(logits[b] - smax);
    red[t] = ls; __syncthreads();
    for (int s = 128; s > 0; s >>= 1) {
        if (t < s) red[t] += red[t + s];
        __syncthreads();
    }
    float denom = red[0]; __syncthreads();
    float inv = (denom > 0.f) ? 1.f / denom : 0.f;

    const int h0 = t * 4;
    float g0 = 0.f, g1 = 0.f, g2 = 0.f, g3 = 0.f;
    for (int b = 0; b < BATCH; ++b) {
        if (cids[b] == c) {  // uniform branch
            float wgt = expf(logits[b] - smax) * inv;
            float4 ev = *(const float4*)(emb + (size_t)b * HID + h0);
            g0 = fmaf(wgt, ev.x, g0);
            g1 = fmaf(wgt, ev.y, g1);
            g2 = fmaf(wgt, ev.z, g2);
            g3 = fmaf(wgt, ev.w, g3);
        }
    }
    float4 cw = *(const float4*)(clf_w + h0);
    float ca = g0 * cw.x + g1 * cw.y + g2 * cw.z + g3 * cw.w;
    red[t] = ca; __syncthreads();
    for (int s = 128; s > 0; s >>= 1) {
        if (t < s) red[t] += red[t + s];
        __syncthreads();
    }
    if (t == 0) out[c] = 1.f / (1.f + expf(-(red[0] + clf_b[0])));
}

// ---------------------------------------------------------------------------
extern "C" void kernel_launch(void* const* d_in, const int* in_sizes, int n_in,
                              void* d_out, int out_size, void* d_ws, size_t ws_size,
                              hipStream_t stream) {
    const float* data = (const float*)d_in[0];
    const int*   cid  = (const int*)d_in[1];
    const float* cw1 = (const float*)d_in[2],  * cb1 = (const float*)d_in[3];
    const float* cw2 = (const float*)d_in[4],  * cb2 = (const float*)d_in[5];
    const float* cw3 = (const float*)d_in[6],  * cb3 = (const float*)d_in[7];
    const float* cw4 = (const float*)d_in[8],  * cb4 = (const float*)d_in[9];
    const float* cw5 = (const float*)d_in[10], * cb5 = (const float*)d_in[11];
    const float* fcw = (const float*)d_in[12], * fcb = (const float*)d_in[13];
    const float* aw1 = (const float*)d_in[14], * ab1 = (const float*)d_in[15];
    const float* aw2 = (const float*)d_in[16], * ab2 = (const float*)d_in[17];
    const float* clw = (const float*)d_in[18], * clb = (const float*)d_in[19];
    float* out = (float*)d_out;

    // workspace layout (floats), ping-pong reuse
    float* ws = (float*)d_ws;
    float* x1  = ws;                     // 512* 8*64*64 = 16,777,216
    float* x2  = ws + 16777216;          // 512*16*32*32 =  8,388,608
    float* x3  = ws;                     // reuse
    float* x4  = ws + 16777216;          // reuse
    float* x5  = ws;                     // reuse
    float* emb = ws + 16777216;          // 512*1024
    float* lg  = ws + 16777216 + 524288; // 512

    // grid = (BATCH*PIX/256, Co/CC); CC tuned for >=4 waves/SIMD on deep layers
    conv_pool_relu_k<3,   8,  8, 128><<<dim3(512 * 4096 / 256, 1),  256, 0, stream>>>(data, cw1, cb1, x1);
    conv_pool_relu_k<8,  16,  8,  64><<<dim3(512 * 1024 / 256, 2),  256, 0, stream>>>(x1,   cw2, cb2, x2);
    conv_pool_relu_k<16, 32,  8,  32><<<dim3(512 *  256 / 256, 4),  256, 0, stream>>>(x2,   cw3, cb3, x3);
    conv_pool_relu_k<32, 64,  4,  16><<<dim3(512 *   64 / 256, 16), 256, 0, stream>>>(x3,   cw4, cb4, x4);
    conv_pool_relu_k<64, 128, 4,   8><<<dim3(512 *   16 / 256, 32), 256, 0, stream>>>(x4,   cw5, cb5, x5);

    fc_k<<<dim3(HID / 256, BATCH / 4), 256, 0, stream>>>(x5, fcw, fcb, emb);
    attention_k<<<BATCH, 128, 0, stream>>>(emb, aw1, ab1, aw2, ab2, lg);
    segment_k<<<NSEG, 256, 0, stream>>>(emb, lg, cid, clw, clb, out);
}

// Round 6
// 1169.148 us; speedup vs baseline: 6.1572x; 1.1024x over previous
//
#include <hip/hip_runtime.h>
#include <hip/hip_bf16.h>
#include <math.h>

// Problem constants
#define BATCH 512
#define NSEG  64
#define HID   1024
#define ATT   128

typedef __attribute__((ext_vector_type(8))) __bf16 bf16x8;
typedef __attribute__((ext_vector_type(4))) float  f32x4;

// ---------------------------------------------------------------------------
// conv1: fp32 direct (Ci=3), fused pool+relu. Output NHWC bf16 for conv2-MFMA.
// ---------------------------------------------------------------------------
__global__ __launch_bounds__(256) void conv1_k(
    const float* __restrict__ in, const float* __restrict__ w,
    const float* __restrict__ bias, __bf16* __restrict__ out) {
    constexpr int Ci = 3, CC = 8, Hin = 128;
    constexpr int Hout = Hin / 2;
    constexpr int PIX = Hout * Hout;

    const int tid = blockIdx.x * 256 + threadIdx.x;
    const int pix = tid & (PIX - 1);
    const int b   = tid / PIX;
    const int x   = pix & (Hout - 1);
    const int y   = pix / Hout;

    const float* __restrict__ ibase = in + (size_t)b * Ci * Hin * Hin;
    const int iy0 = 2 * y - 2;
    const int ix0 = 2 * x - 2;
    const bool xL = (x >= 1);
    const bool xR = (x < Hout - 1);

    bool vy[6];
    int rb[6];
#pragma unroll
    for (int d = 0; d < 6; ++d) {
        int iy = iy0 + d;
        vy[d] = (unsigned)iy < (unsigned)Hin;
        rb[d] = vy[d] ? iy * Hin : 0;
    }

    float acc[CC * 4];
#pragma unroll
    for (int i = 0; i < CC * 4; ++i) acc[i] = 0.f;

    for (int ci = 0; ci < Ci; ++ci) {
        const float* __restrict__ ip = ibase + ci * Hin * Hin;
        float r[36];
#pragma unroll
        for (int dy = 0; dy < 6; ++dy) {
            bool vA = vy[dy] && xL;
            bool vC = vy[dy] && xR;
            float2 pA = *(const float2*)(ip + (vA ? rb[dy] + ix0 : 0));
            float2 pB = *(const float2*)(ip + rb[dy] + ix0 + 2);
            float2 pC = *(const float2*)(ip + (vC ? rb[dy] + ix0 + 4 : 0));
            r[dy * 6 + 0] = vA ? pA.x : 0.f;
            r[dy * 6 + 1] = vA ? pA.y : 0.f;
            r[dy * 6 + 2] = vy[dy] ? pB.x : 0.f;
            r[dy * 6 + 3] = vy[dy] ? pB.y : 0.f;
            r[dy * 6 + 4] = vC ? pC.x : 0.f;
            r[dy * 6 + 5] = vC ? pC.y : 0.f;
        }
#pragma unroll
        for (int cc = 0; cc < CC; ++cc) {
            const float* __restrict__ wp = w + (cc * Ci + ci) * 25;  // uniform
#pragma unroll
            for (int kh = 0; kh < 5; ++kh) {
#pragma unroll
                for (int kw = 0; kw < 5; ++kw) {
                    float wv = wp[kh * 5 + kw];
                    acc[cc * 4 + 0] = fmaf(r[kh * 6 + kw],           wv, acc[cc * 4 + 0]);
                    acc[cc * 4 + 1] = fmaf(r[kh * 6 + kw + 1],       wv, acc[cc * 4 + 1]);
                    acc[cc * 4 + 2] = fmaf(r[(kh + 1) * 6 + kw],     wv, acc[cc * 4 + 2]);
                    acc[cc * 4 + 3] = fmaf(r[(kh + 1) * 6 + kw + 1], wv, acc[cc * 4 + 3]);
                }
            }
        }
    }

    bf16x8 ov;
#pragma unroll
    for (int cc = 0; cc < CC; ++cc) {
        float m = fmaxf(fmaxf(acc[cc * 4 + 0], acc[cc * 4 + 1]),
                        fmaxf(acc[cc * 4 + 2], acc[cc * 4 + 3])) + bias[cc];
        ov[cc] = (__bf16)fmaxf(m, 0.f);
    }
    *(bf16x8*)(out + ((size_t)b * PIX + pix) * 8) = ov;
}

// ---------------------------------------------------------------------------
// Weight pre-convert: w[co][ci][kh][kw] fp32 -> wt[k/8][co][k%8] bf16,
// k = (kh*5+kw)*Ci + ci  (A-frag: lane m=lane&15 reads 16B = A[co][k8*8..+7]).
// ---------------------------------------------------------------------------
template<int Ci, int Co>
__global__ void wconv_k(const float* __restrict__ w, __bf16* __restrict__ wt) {
    const int n = 25 * Ci * Co;
    int t = blockIdx.x * 256 + threadIdx.x;
    if (t >= n) return;
    int j  = t & 7;
    int t2 = t >> 3;
    int co = t2 % Co;
    int k8 = t2 / Co;
    int k  = k8 * 8 + j;
    int tap = k / Ci, ci = k % Ci;
    int kh = tap / 5, kw = tap % 5;
    wt[t] = (__bf16)w[((co * Ci + ci) * 25) + kh * 5 + kw];
}

// ---------------------------------------------------------------------------
// BISECTION ROUND: MFMA implicit-GEMM conv for LAYER 2 ONLY.
// Ci=8, Co=16, H=W=64.  X: NHWC bf16.  Output: NCHW fp32 (for fp32 conv3).
// Hardened vs round 5: separate xs/cs LDS arrays (no aliasing), no LUT
// (arith tap/5), if-based zero masking.
// ---------------------------------------------------------------------------
__global__ __launch_bounds__(256) void conv2_mfma_k(
    const __bf16* __restrict__ X, const __bf16* __restrict__ Wt,
    const float* __restrict__ bias, float* __restrict__ out) {
    constexpr int Ci = 8, Co = 16, H = 64, W = 64;
    constexpr int NPIX = H * W, NTOT = BATCH * NPIX;
    constexpr int HALO = 2 * W + 2, SPAN = 256 + 2 * HALO, STR = Ci + 8;
    constexpr int K = 25 * Ci, KT = (K + 31) / 32;   // 200, 7
    constexpr int LOGW = 6;

    __shared__ __align__(16) __bf16 xs[SPAN * STR];   // 516*16*2 = 16512 B
    __shared__ float cs[16 * 256];                    // 16384 B

    const int tid  = threadIdx.x;
    const int pos0 = blockIdx.x * 256;

    // ---- stage input tile + halo (clamped at array ends; masked at use) ----
    for (int p = tid; p < SPAN; p += 256) {
        int gp = pos0 - HALO + p;
        gp = gp < 0 ? 0 : (gp > NTOT - 1 ? NTOT - 1 : gp);
        *(bf16x8*)(xs + p * STR) = *(const bf16x8*)(X + (size_t)gp * Ci);
    }
    __syncthreads();

    const int lane = tid & 63, wave = tid >> 6;
    const int quad = lane >> 4, l15 = lane & 15;

    int px[4], py[4], pbase[4];
    f32x4 acc[4];
#pragma unroll
    for (int f = 0; f < 4; ++f) {
        int pl = wave * 64 + f * 16 + l15;
        int p  = pos0 + pl;
        px[f] = p & (W - 1);
        py[f] = (p >> LOGW) & (H - 1);
        pbase[f] = (pl + HALO) * STR;
        acc[f] = f32x4{0.f, 0.f, 0.f, 0.f};
    }
    const bf16x8 BZ = {};

    for (int kt = 0; kt < KT; ++kt) {
        int k8 = kt * 4 + quad;
        int kk = k8 * 8;
        bool kok = kk < K;
        int kkc  = kok ? kk : 0;
        int tap  = kkc >> 3;            // k = tap*8 + ci
        int dy   = tap / 5 - 2;
        int dx   = tap % 5 - 2;
        int shift = dy * W + dx;
        bf16x8 av = *(const bf16x8*)(Wt + ((size_t)(kok ? k8 : 0) * Co + l15) * 8);
#pragma unroll
        for (int f = 0; f < 4; ++f) {
            bf16x8 bv = *(const bf16x8*)(xs + pbase[f] + shift * STR);
            bool valid = kok && ((unsigned)(px[f] + dx) < (unsigned)W)
                             && ((unsigned)(py[f] + dy) < (unsigned)H);
            if (!valid) bv = BZ;
            acc[f] = __builtin_amdgcn_mfma_f32_16x16x32_bf16(av, bv, acc[f], 0, 0, 0);
        }
    }

    // ---- acc -> LDS [co16][pos256]  (C/D: col=lane&15=pos, row=quad*4+reg)
#pragma unroll
    for (int f = 0; f < 4; ++f) {
        int pl = wave * 64 + f * 16 + l15;
#pragma unroll
        for (int r = 0; r < 4; ++r) cs[(quad * 4 + r) * 256 + pl] = acc[f][r];
    }
    __syncthreads();

    // ---- pool 2x2 + bias + relu -> NCHW fp32 [b][co][oy32][ox32] ----
    {
        int opos = tid >> 2;            // 64 pooled outputs per tile
        int cog  = (tid & 3) * 4;
        int ocol = opos & (W / 2 - 1);
        int orow = opos >> (LOGW - 1);
        int pl0  = (orow * 2) * W + ocol * 2;
        int p    = pos0 + pl0;
        int b    = p >> (2 * LOGW);
        int yy   = (p >> LOGW) & (H - 1);
        int xx   = p & (W - 1);
        int oy = yy >> 1, ox = xx >> 1;
#pragma unroll
        for (int i = 0; i < 4; ++i) {
            int cr = cog + i;
            float v0 = cs[cr * 256 + pl0],     v1 = cs[cr * 256 + pl0 + 1];
            float v2 = cs[cr * 256 + pl0 + W], v3 = cs[cr * 256 + pl0 + W + 1];
            float m = fmaxf(fmaxf(v0, v1), fmaxf(v2, v3)) + bias[cr];
            out[((size_t)b * Co + cr) * 1024 + oy * 32 + ox] = fmaxf(m, 0.f);
        }
    }
}

// ---------------------------------------------------------------------------
// fp32 direct conv+pool+relu (round-4 verified), NCHW fp32 in/out.
// ---------------------------------------------------------------------------
template<int Ci, int Co, int CC, int Hin>
__global__ __launch_bounds__(256) void conv_pool_relu_k(
    const float* __restrict__ in, const float* __restrict__ w,
    const float* __restrict__ bias, float* __restrict__ out) {
    constexpr int Hout = Hin / 2;
    constexpr int PIX = Hout * Hout;

    const int tid = blockIdx.x * 256 + threadIdx.x;
    const int pix = tid & (PIX - 1);
    const int b   = tid / PIX;
    const int x   = pix & (Hout - 1);
    const int y   = pix / Hout;
    const int co0 = blockIdx.y * CC;

    const float* __restrict__ wbase = w + (size_t)co0 * (Ci * 25);
    const float* __restrict__ ibase = in + (size_t)b * Ci * Hin * Hin;

    const int iy0 = 2 * y - 2;
    const int ix0 = 2 * x - 2;
    const bool xL = (x >= 1);
    const bool xR = (x < Hout - 1);

    bool vy[6];
    int rb[6];
#pragma unroll
    for (int d = 0; d < 6; ++d) {
        int iy = iy0 + d;
        vy[d] = (unsigned)iy < (unsigned)Hin;
        rb[d] = vy[d] ? iy * Hin : 0;
    }

    float acc[CC * 4];
#pragma unroll
    for (int i = 0; i < CC * 4; ++i) acc[i] = 0.f;

    for (int ci = 0; ci < Ci; ++ci) {
        const float* __restrict__ ip = ibase + ci * Hin * Hin;
        float r[36];
#pragma unroll
        for (int dy = 0; dy < 6; ++dy) {
            bool vA = vy[dy] && xL;
            bool vC = vy[dy] && xR;
            float2 pA = *(const float2*)(ip + (vA ? rb[dy] + ix0 : 0));
            float2 pB = *(const float2*)(ip + rb[dy] + ix0 + 2);
            float2 pC = *(const float2*)(ip + (vC ? rb[dy] + ix0 + 4 : 0));
            r[dy * 6 + 0] = vA ? pA.x : 0.f;
            r[dy * 6 + 1] = vA ? pA.y : 0.f;
            r[dy * 6 + 2] = vy[dy] ? pB.x : 0.f;
            r[dy * 6 + 3] = vy[dy] ? pB.y : 0.f;
            r[dy * 6 + 4] = vC ? pC.x : 0.f;
            r[dy * 6 + 5] = vC ? pC.y : 0.f;
        }
#pragma unroll
        for (int cc = 0; cc < CC; ++cc) {
            const float* __restrict__ wp = wbase + cc * (Ci * 25) + ci * 25;
#pragma unroll
            for (int kh = 0; kh < 5; ++kh) {
#pragma unroll
                for (int kw = 0; kw < 5; ++kw) {
                    float wv = wp[kh * 5 + kw];
                    acc[cc * 4 + 0] = fmaf(r[kh * 6 + kw],           wv, acc[cc * 4 + 0]);
                    acc[cc * 4 + 1] = fmaf(r[kh * 6 + kw + 1],       wv, acc[cc * 4 + 1]);
                    acc[cc * 4 + 2] = fmaf(r[(kh + 1) * 6 + kw],     wv, acc[cc * 4 + 2]);
                    acc[cc * 4 + 3] = fmaf(r[(kh + 1) * 6 + kw + 1], wv, acc[cc * 4 + 3]);
                }
            }
        }
    }

#pragma unroll
    for (int cc = 0; cc < CC; ++cc) {
        float m = fmaxf(fmaxf(acc[cc * 4 + 0], acc[cc * 4 + 1]),
                        fmaxf(acc[cc * 4 + 2], acc[cc * 4 + 3])) + bias[co0 + cc];
        out[((size_t)b * Co + co0 + cc) * PIX + pix] = fmaxf(m, 0.f);
    }
}

// ---------------------------------------------------------------------------
// FC
// ---------------------------------------------------------------------------
__global__ __launch_bounds__(256) void fc_k(
    const float* __restrict__ flat, const float* __restrict__ w,
    const float* __restrict__ bias, float* __restrict__ out) {
    const int t = threadIdx.x;
    const int o = blockIdx.x * 256 + t;
    const int b0 = blockIdx.y * 4;
    __shared__ float a[4 * 2048];
    const float* src = flat + (size_t)b0 * 2048;
    for (int i = t * 4; i < 4 * 2048; i += 256 * 4)
        *(float4*)(a + i) = *(const float4*)(src + i);
    __syncthreads();

    float acc0 = 0.f, acc1 = 0.f, acc2 = 0.f, acc3 = 0.f;
    const float* wr = w + (size_t)o * 2048;
    for (int k = 0; k < 2048; k += 4) {
        float4 wv = *(const float4*)(wr + k);
        float4 a0 = *(const float4*)(a + 0 * 2048 + k);
        float4 a1 = *(const float4*)(a + 1 * 2048 + k);
        float4 a2 = *(const float4*)(a + 2 * 2048 + k);
        float4 a3 = *(const float4*)(a + 3 * 2048 + k);
        acc0 += wv.x * a0.x + wv.y * a0.y + wv.z * a0.z + wv.w * a0.w;
        acc1 += wv.x * a1.x + wv.y * a1.y + wv.z * a1.z + wv.w * a1.w;
        acc2 += wv.x * a2.x + wv.y * a2.y + wv.z * a2.z + wv.w * a2.w;
        acc3 += wv.x * a3.x + wv.y * a3.y + wv.z * a3.z + wv.w * a3.w;
    }
    float bv = bias[o];
    out[(size_t)(b0 + 0) * 1024 + o] = acc0 + bv;
    out[(size_t)(b0 + 1) * 1024 + o] = acc1 + bv;
    out[(size_t)(b0 + 2) * 1024 + o] = acc2 + bv;
    out[(size_t)(b0 + 3) * 1024 + o] = acc3 + bv;
}

// ---------------------------------------------------------------------------
// Attention
// ---------------------------------------------------------------------------
__global__ __launch_bounds__(128) void attention_k(
    const float* __restrict__ emb, const float* __restrict__ w1,
    const float* __restrict__ b1, const float* __restrict__ w2,
    const float* __restrict__ b2, float* __restrict__ logits) {
    const int b = blockIdx.x;
    const int j = threadIdx.x;
    __shared__ float es[HID];
    for (int k = j; k < HID; k += 128) es[k] = emb[(size_t)b * HID + k];
    __syncthreads();

    float s = b1[j];
    const float* wr = w1 + (size_t)j * HID;
    for (int k = 0; k < HID; k += 4) {
        float4 wv = *(const float4*)(wr + k);
        float4 ev = *(const float4*)(es + k);
        s += wv.x * ev.x + wv.y * ev.y + wv.z * ev.z + wv.w * ev.w;
    }
    float v = tanhf(s) * w2[j];
#pragma unroll
    for (int off = 32; off > 0; off >>= 1) v += __shfl_down(v, off);
    __shared__ float wsum[2];
    if ((j & 63) == 0) wsum[j >> 6] = v;
    __syncthreads();
    if (j == 0) logits[b] = wsum[0] + wsum[1] + b2[0];
}

// ---------------------------------------------------------------------------
// Segment softmax + aggregation + classifier
// ---------------------------------------------------------------------------
__global__ __launch_bounds__(256) void segment_k(
    const float* __restrict__ emb, const float* __restrict__ logits,
    const int* __restrict__ cid, const float* __restrict__ clf_w,
    const float* __restrict__ clf_b, float* __restrict__ out) {
    const int c = blockIdx.x;
    const int t = threadIdx.x;
    __shared__ int cids[BATCH];
    __shared__ float red[256];
    for (int i = t; i < BATCH; i += 256) cids[i] = cid[i];
    __syncthreads();

    float lm = -1e30f;
    for (int b = t; b < BATCH; b += 256)
        if (cids[b] == c) lm = fmaxf(lm, logits[b]);
    red[t] = lm; __syncthreads();
    for (int s = 128; s > 0; s >>= 1) {
        if (t < s) red[t] = fmaxf(red[t], red[t + s]);
        __syncthreads();
    }
    float smax = red[0]; __syncthreads();

    float ls = 0.f;
    for (int b = t; b < BATCH; b += 256)
        if (cids[b] == c) ls += expf(logits[b] - smax);
    red[t] = ls; __syncthreads();
    for (int s = 128; s > 0; s >>= 1) {
        if (t < s) red[t] += red[t + s];
        __syncthreads();
    }
    float denom = red[0]; __syncthreads();
    float inv = (denom > 0.f) ? 1.f / denom : 0.f;

    const int h0 = t * 4;
    float g0 = 0.f, g1 = 0.f, g2 = 0.f, g3 = 0.f;
    for (int b = 0; b < BATCH; ++b) {
        if (cids[b] == c) {
            float wgt = expf(logits[b] - smax) * inv;
            float4 ev = *(const float4*)(emb + (size_t)b * HID + h0);
            g0 = fmaf(wgt, ev.x, g0);
            g1 = fmaf(wgt, ev.y, g1);
            g2 = fmaf(wgt, ev.z, g2);
            g3 = fmaf(wgt, ev.w, g3);
        }
    }
    float4 cw = *(const float4*)(clf_w + h0);
    float ca = g0 * cw.x + g1 * cw.y + g2 * cw.z + g3 * cw.w;
    red[t] = ca; __syncthreads();
    for (int s = 128; s > 0; s >>= 1) {
        if (t < s) red[t] += red[t + s];
        __syncthreads();
    }
    if (t == 0) out[c] = 1.f / (1.f + expf(-(red[0] + clf_b[0])));
}

// ---------------------------------------------------------------------------
extern "C" void kernel_launch(void* const* d_in, const int* in_sizes, int n_in,
                              void* d_out, int out_size, void* d_ws, size_t ws_size,
                              hipStream_t stream) {
    const float* data = (const float*)d_in[0];
    const int*   cid  = (const int*)d_in[1];
    const float* cw1 = (const float*)d_in[2],  * cb1 = (const float*)d_in[3];
    const float* cw2 = (const float*)d_in[4],  * cb2 = (const float*)d_in[5];
    const float* cw3 = (const float*)d_in[6],  * cb3 = (const float*)d_in[7];
    const float* cw4 = (const float*)d_in[8],  * cb4 = (const float*)d_in[9];
    const float* cw5 = (const float*)d_in[10], * cb5 = (const float*)d_in[11];
    const float* fcw = (const float*)d_in[12], * fcb = (const float*)d_in[13];
    const float* aw1 = (const float*)d_in[14], * ab1 = (const float*)d_in[15];
    const float* aw2 = (const float*)d_in[16], * ab2 = (const float*)d_in[17];
    const float* clw = (const float*)d_in[18], * clb = (const float*)d_in[19];
    float* out = (float*)d_out;

    // workspace (bytes), non-overlapping, ~98.6 MB
    char* wsb = (char*)d_ws;
    __bf16* x1  = (__bf16*)(wsb);              // 512*4096*8  bf16 = 33,554,432 B
    float*  x2  = (float*) (wsb + 33554432);   // 512*16*1024 f32  = 33,554,432 B
    float*  x3  = (float*) (wsb + 67108864);   // 512*32*256  f32  = 16,777,216 B
    float*  x4  = (float*) (wsb + 83886080);   // 512*64*64   f32  =  8,388,608 B
    float*  x5  = (float*) (wsb + 92274688);   // 512*2048    f32  =  4,194,304 B
    float*  emb = (float*) (wsb + 96468992);   // 512*1024    f32  =  2,097,152 B
    float*  lg  = (float*) (wsb + 98566144);   // 512 f32
    __bf16* wt2 = (__bf16*)(wsb + 98568192);   // 3200 bf16

    wconv_k<8, 16><<<(3200 + 255) / 256, 256, 0, stream>>>(cw2, wt2);

    conv1_k<<<512 * 4096 / 256, 256, 0, stream>>>(data, cw1, cb1, x1);

    conv2_mfma_k<<<8192, 256, 0, stream>>>(x1, wt2, cb2, x2);   // MFMA under test

    conv_pool_relu_k<16, 32,  8, 32><<<dim3(512 * 256 / 256, 4),  256, 0, stream>>>(x2, cw3, cb3, x3);
    conv_pool_relu_k<32, 64,  4, 16><<<dim3(512 *  64 / 256, 16), 256, 0, stream>>>(x3, cw4, cb4, x4);
    conv_pool_relu_k<64, 128, 4,  8><<<dim3(512 *  16 / 256, 32), 256, 0, stream>>>(x4, cw5, cb5, x5);

    fc_k<<<dim3(HID / 256, BATCH / 4), 256, 0, stream>>>(x5, fcw, fcb, emb);
    attention_k<<<BATCH, 128, 0, stream>>>(emb, aw1, ab1, aw2, ab2, lg);
    segment_k<<<NSEG, 256, 0, stream>>>(emb, lg, cid, clw, clb, out);
}

// Round 7
// 582.895 us; speedup vs baseline: 12.3499x; 2.0058x over previous
//
#include <hip/hip_runtime.h>
#include <hip/hip_bf16.h>
#include <math.h>

// Problem constants
#define BATCH 512
#define NSEG  64
#define HID   1024
#define ATT   128

typedef __attribute__((ext_vector_type(8))) __bf16 bf16x8;
typedef __attribute__((ext_vector_type(4))) float  f32x4;

// ---------------------------------------------------------------------------
// conv1: fp32 direct (Ci=3), fused pool+relu. Output NHWC bf16 for conv2-MFMA.
// ---------------------------------------------------------------------------
__global__ __launch_bounds__(256) void conv1_k(
    const float* __restrict__ in, const float* __restrict__ w,
    const float* __restrict__ bias, __bf16* __restrict__ out) {
    constexpr int Ci = 3, CC = 8, Hin = 128;
    constexpr int Hout = Hin / 2;
    constexpr int PIX = Hout * Hout;

    const int tid = blockIdx.x * 256 + threadIdx.x;
    const int pix = tid & (PIX - 1);
    const int b   = tid / PIX;
    const int x   = pix & (Hout - 1);
    const int y   = pix / Hout;

    const float* __restrict__ ibase = in + (size_t)b * Ci * Hin * Hin;
    const int iy0 = 2 * y - 2;
    const int ix0 = 2 * x - 2;
    const bool xL = (x >= 1);
    const bool xR = (x < Hout - 1);

    bool vy[6];
    int rb[6];
#pragma unroll
    for (int d = 0; d < 6; ++d) {
        int iy = iy0 + d;
        vy[d] = (unsigned)iy < (unsigned)Hin;
        rb[d] = vy[d] ? iy * Hin : 0;
    }

    float acc[CC * 4];
#pragma unroll
    for (int i = 0; i < CC * 4; ++i) acc[i] = 0.f;

    for (int ci = 0; ci < Ci; ++ci) {
        const float* __restrict__ ip = ibase + ci * Hin * Hin;
        float r[36];
#pragma unroll
        for (int dy = 0; dy < 6; ++dy) {
            bool vA = vy[dy] && xL;
            bool vC = vy[dy] && xR;
            float2 pA = *(const float2*)(ip + (vA ? rb[dy] + ix0 : 0));
            float2 pB = *(const float2*)(ip + rb[dy] + ix0 + 2);
            float2 pC = *(const float2*)(ip + (vC ? rb[dy] + ix0 + 4 : 0));
            r[dy * 6 + 0] = vA ? pA.x : 0.f;
            r[dy * 6 + 1] = vA ? pA.y : 0.f;
            r[dy * 6 + 2] = vy[dy] ? pB.x : 0.f;
            r[dy * 6 + 3] = vy[dy] ? pB.y : 0.f;
            r[dy * 6 + 4] = vC ? pC.x : 0.f;
            r[dy * 6 + 5] = vC ? pC.y : 0.f;
        }
#pragma unroll
        for (int cc = 0; cc < CC; ++cc) {
            const float* __restrict__ wp = w + (cc * Ci + ci) * 25;  // uniform
#pragma unroll
            for (int kh = 0; kh < 5; ++kh) {
#pragma unroll
                for (int kw = 0; kw < 5; ++kw) {
                    float wv = wp[kh * 5 + kw];
                    acc[cc * 4 + 0] = fmaf(r[kh * 6 + kw],           wv, acc[cc * 4 + 0]);
                    acc[cc * 4 + 1] = fmaf(r[kh * 6 + kw + 1],       wv, acc[cc * 4 + 1]);
                    acc[cc * 4 + 2] = fmaf(r[(kh + 1) * 6 + kw],     wv, acc[cc * 4 + 2]);
                    acc[cc * 4 + 3] = fmaf(r[(kh + 1) * 6 + kw + 1], wv, acc[cc * 4 + 3]);
                }
            }
        }
    }

    bf16x8 ov;
#pragma unroll
    for (int cc = 0; cc < CC; ++cc) {
        float m = fmaxf(fmaxf(acc[cc * 4 + 0], acc[cc * 4 + 1]),
                        fmaxf(acc[cc * 4 + 2], acc[cc * 4 + 3])) + bias[cc];
        ov[cc] = (__bf16)fmaxf(m, 0.f);
    }
    *(bf16x8*)(out + ((size_t)b * PIX + pix) * 8) = ov;
}

// ---------------------------------------------------------------------------
// Weight pre-convert: w[co][ci][kh][kw] fp32 -> wt[k/8][co][k%8] bf16,
// k = (kh*5+kw)*Ci + ci  (A-frag: lane m=lane&15 reads 16B = A[co][k8*8..+7]).
// ---------------------------------------------------------------------------
template<int Ci, int Co>
__global__ void wconv_k(const float* __restrict__ w, __bf16* __restrict__ wt) {
    const int n = 25 * Ci * Co;
    int t = blockIdx.x * 256 + threadIdx.x;
    if (t >= n) return;
    int j  = t & 7;
    int t2 = t >> 3;
    int co = t2 % Co;
    int k8 = t2 / Co;
    int k  = k8 * 8 + j;
    int tap = k / Ci, ci = k % Ci;
    int kh = tap / 5, kw = tap % 5;
    wt[t] = (__bf16)w[((co * Ci + ci) * 25) + kh * 5 + kw];
}

// ---------------------------------------------------------------------------
// MFMA implicit-GEMM conv5x5(same) + bias + maxpool2 + relu.
// Hardened form verified on conv2 in round 6: separate xs/cs LDS arrays
// (NO char-buffer aliasing -- that was round-5's NaN), arithmetic tap,
// if-based masking.  X: NHWC bf16 [B*H*W][Ci].  Wt: A-frag layout (above).
// GEMM: K=25*Ci (k=tap*Ci+ci), M=16 co per WG (blockIdx.y), N=256 positions
// per WG (4 waves x 4 col-frags).  Output: NHWC bf16, or NCHW fp32 (conv5).
// ---------------------------------------------------------------------------
template<int Ci, int Co, int H, bool FP32OUT>
__global__ __launch_bounds__(256) void conv_mfma_k(
    const __bf16* __restrict__ X, const __bf16* __restrict__ Wt,
    const float* __restrict__ bias, void* __restrict__ outp) {
    constexpr int W = H, NPIX = H * W, NTOT = BATCH * NPIX;
    constexpr int HALO = 2 * W + 2, SPAN = 256 + 2 * HALO, STR = Ci + 8;
    constexpr int K = 25 * Ci, KT = (K + 31) / 32;
    constexpr int LOGW = (W == 64 ? 6 : (W == 32 ? 5 : (W == 16 ? 4 : 3)));

    __shared__ __align__(16) __bf16 xs[SPAN * STR];
    __shared__ float cs[16 * 256];

    const int tid  = threadIdx.x;
    const int pos0 = blockIdx.x * 256;
    const int co0  = blockIdx.y * 16;

    // ---- stage input tile + halo (clamped at array ends; masked at use) ----
    constexpr int C8 = Ci / 8;
    for (int i = tid; i < SPAN * C8; i += 256) {
        int p   = i / C8;
        int cio = (i % C8) * 8;
        int gp  = pos0 - HALO + p;
        gp = gp < 0 ? 0 : (gp > NTOT - 1 ? NTOT - 1 : gp);
        *(bf16x8*)(xs + p * STR + cio) = *(const bf16x8*)(X + (size_t)gp * Ci + cio);
    }
    __syncthreads();

    const int lane = tid & 63, wave = tid >> 6;
    const int quad = lane >> 4, l15 = lane & 15;

    int px[4], py[4], pbase[4];
    f32x4 acc[4];
#pragma unroll
    for (int f = 0; f < 4; ++f) {
        int pl = wave * 64 + f * 16 + l15;
        int p  = pos0 + pl;
        px[f] = p & (W - 1);
        py[f] = (p >> LOGW) & (H - 1);
        pbase[f] = (pl + HALO) * STR;
        acc[f] = f32x4{0.f, 0.f, 0.f, 0.f};
    }
    const bf16x8 BZ = {};

    for (int kt = 0; kt < KT; ++kt) {
        int k8 = kt * 4 + quad;
        int kk = k8 * 8;
        bool kok = kk < K;
        int kkc  = kok ? kk : 0;
        int tap  = kkc / Ci;            // Ci is a power of two
        int cib  = kkc % Ci;            // multiple of 8: the 8 k's share one tap
        int dy   = tap / 5 - 2;
        int dx   = tap % 5 - 2;
        int shift = dy * W + dx;
        bf16x8 av = *(const bf16x8*)(Wt + ((size_t)(kok ? k8 : 0) * Co + co0 + l15) * 8);
#pragma unroll
        for (int f = 0; f < 4; ++f) {
            bf16x8 bv = *(const bf16x8*)(xs + pbase[f] + shift * STR + cib);
            bool valid = kok && ((unsigned)(px[f] + dx) < (unsigned)W)
                             && ((unsigned)(py[f] + dy) < (unsigned)H);
            if (!valid) bv = BZ;
            acc[f] = __builtin_amdgcn_mfma_f32_16x16x32_bf16(av, bv, acc[f], 0, 0, 0);
        }
    }

    // ---- acc -> LDS [co16][pos256]  (C/D: col=lane&15=pos, row=quad*4+reg)
#pragma unroll
    for (int f = 0; f < 4; ++f) {
        int pl = wave * 64 + f * 16 + l15;
#pragma unroll
        for (int r = 0; r < 4; ++r) cs[(quad * 4 + r) * 256 + pl] = acc[f][r];
    }
    __syncthreads();

    // ---- pool 2x2 + bias + relu; 64 pooled outputs per tile, 4 co each ----
    {
        int opos = tid >> 2;
        int cog  = (tid & 3) * 4;
        int ocol = opos & (W / 2 - 1);
        int orow = opos >> (LOGW - 1);
        int pl0  = (orow * 2) * W + ocol * 2;
        int p    = pos0 + pl0;
        int b    = p >> (2 * LOGW);
        int yy   = (p >> LOGW) & (H - 1);
        int xx   = p & (W - 1);
        int oy = yy >> 1, ox = xx >> 1;
#pragma unroll
        for (int i = 0; i < 4; ++i) {
            int cr = cog + i;
            float v0 = cs[cr * 256 + pl0],     v1 = cs[cr * 256 + pl0 + 1];
            float v2 = cs[cr * 256 + pl0 + W], v3 = cs[cr * 256 + pl0 + W + 1];
            float m = fmaxf(fmaxf(v0, v1), fmaxf(v2, v3)) + bias[co0 + cr];
            m = fmaxf(m, 0.f);
            if (FP32OUT) {
                ((float*)outp)[(size_t)b * 2048 + (co0 + cr) * 16 + oy * 4 + ox] = m;
            } else {
                ((__bf16*)outp)[((size_t)((b * (H / 2) + oy) * (W / 2)) + ox) * Co + co0 + cr] = (__bf16)m;
            }
        }
    }
}

// ---------------------------------------------------------------------------
// FC
// ---------------------------------------------------------------------------
__global__ __launch_bounds__(256) void fc_k(
    const float* __restrict__ flat, const float* __restrict__ w,
    const float* __restrict__ bias, float* __restrict__ out) {
    const int t = threadIdx.x;
    const int o = blockIdx.x * 256 + t;
    const int b0 = blockIdx.y * 4;
    __shared__ float a[4 * 2048];
    const float* src = flat + (size_t)b0 * 2048;
    for (int i = t * 4; i < 4 * 2048; i += 256 * 4)
        *(float4*)(a + i) = *(const float4*)(src + i);
    __syncthreads();

    float acc0 = 0.f, acc1 = 0.f, acc2 = 0.f, acc3 = 0.f;
    const float* wr = w + (size_t)o * 2048;
    for (int k = 0; k < 2048; k += 4) {
        float4 wv = *(const float4*)(wr + k);
        float4 a0 = *(const float4*)(a + 0 * 2048 + k);
        float4 a1 = *(const float4*)(a + 1 * 2048 + k);
        float4 a2 = *(const float4*)(a + 2 * 2048 + k);
        float4 a3 = *(const float4*)(a + 3 * 2048 + k);
        acc0 += wv.x * a0.x + wv.y * a0.y + wv.z * a0.z + wv.w * a0.w;
        acc1 += wv.x * a1.x + wv.y * a1.y + wv.z * a1.z + wv.w * a1.w;
        acc2 += wv.x * a2.x + wv.y * a2.y + wv.z * a2.z + wv.w * a2.w;
        acc3 += wv.x * a3.x + wv.y * a3.y + wv.z * a3.z + wv.w * a3.w;
    }
    float bv = bias[o];
    out[(size_t)(b0 + 0) * 1024 + o] = acc0 + bv;
    out[(size_t)(b0 + 1) * 1024 + o] = acc1 + bv;
    out[(size_t)(b0 + 2) * 1024 + o] = acc2 + bv;
    out[(size_t)(b0 + 3) * 1024 + o] = acc3 + bv;
}

// ---------------------------------------------------------------------------
// Attention
// ---------------------------------------------------------------------------
__global__ __launch_bounds__(128) void attention_k(
    const float* __restrict__ emb, const float* __restrict__ w1,
    const float* __restrict__ b1, const float* __restrict__ w2,
    const float* __restrict__ b2, float* __restrict__ logits) {
    const int b = blockIdx.x;
    const int j = threadIdx.x;
    __shared__ float es[HID];
    for (int k = j; k < HID; k += 128) es[k] = emb[(size_t)b * HID + k];
    __syncthreads();

    float s = b1[j];
    const float* wr = w1 + (size_t)j * HID;
    for (int k = 0; k < HID; k += 4) {
        float4 wv = *(const float4*)(wr + k);
        float4 ev = *(const float4*)(es + k);
        s += wv.x * ev.x + wv.y * ev.y + wv.z * ev.z + wv.w * ev.w;
    }
    float v = tanhf(s) * w2[j];
#pragma unroll
    for (int off = 32; off > 0; off >>= 1) v += __shfl_down(v, off);
    __shared__ float wsum[2];
    if ((j & 63) == 0) wsum[j >> 6] = v;
    __syncthreads();
    if (j == 0) logits[b] = wsum[0] + wsum[1] + b2[0];
}

// ---------------------------------------------------------------------------
// Segment softmax + aggregation + classifier
// ---------------------------------------------------------------------------
__global__ __launch_bounds__(256) void segment_k(
    const float* __restrict__ emb, const float* __restrict__ logits,
    const int* __restrict__ cid, const float* __restrict__ clf_w,
    const float* __restrict__ clf_b, float* __restrict__ out) {
    const int c = blockIdx.x;
    const int t = threadIdx.x;
    __shared__ int cids[BATCH];
    __shared__ float red[256];
    for (int i = t; i < BATCH; i += 256) cids[i] = cid[i];
    __syncthreads();

    float lm = -1e30f;
    for (int b = t; b < BATCH; b += 256)
        if (cids[b] == c) lm = fmaxf(lm, logits[b]);
    red[t] = lm; __syncthreads();
    for (int s = 128; s > 0; s >>= 1) {
        if (t < s) red[t] = fmaxf(red[t], red[t + s]);
        __syncthreads();
    }
    float smax = red[0]; __syncthreads();

    float ls = 0.f;
    for (int b = t; b < BATCH; b += 256)
        if (cids[b] == c) ls += expf(logits[b] - smax);
    red[t] = ls; __syncthreads();
    for (int s = 128; s > 0; s >>= 1) {
        if (t < s) red[t] += red[t + s];
        __syncthreads();
    }
    float denom = red[0]; __syncthreads();
    float inv = (denom > 0.f) ? 1.f / denom : 0.f;

    const int h0 = t * 4;
    float g0 = 0.f, g1 = 0.f, g2 = 0.f, g3 = 0.f;
    for (int b = 0; b < BATCH; ++b) {
        if (cids[b] == c) {
            float wgt = expf(logits[b] - smax) * inv;
            float4 ev = *(const float4*)(emb + (size_t)b * HID + h0);
            g0 = fmaf(wgt, ev.x, g0);
            g1 = fmaf(wgt, ev.y, g1);
            g2 = fmaf(wgt, ev.z, g2);
            g3 = fmaf(wgt, ev.w, g3);
        }
    }
    float4 cw = *(const float4*)(clf_w + h0);
    float ca = g0 * cw.x + g1 * cw.y + g2 * cw.z + g3 * cw.w;
    red[t] = ca; __syncthreads();
    for (int s = 128; s > 0; s >>= 1) {
        if (t < s) red[t] += red[t + s];
        __syncthreads();
    }
    if (t == 0) out[c] = 1.f / (1.f + expf(-(red[0] + clf_b[0])));
}

// ---------------------------------------------------------------------------
extern "C" void kernel_launch(void* const* d_in, const int* in_sizes, int n_in,
                              void* d_out, int out_size, void* d_ws, size_t ws_size,
                              hipStream_t stream) {
    const float* data = (const float*)d_in[0];
    const int*   cid  = (const int*)d_in[1];
    const float* cw1 = (const float*)d_in[2],  * cb1 = (const float*)d_in[3];
    const float* cw2 = (const float*)d_in[4],  * cb2 = (const float*)d_in[5];
    const float* cw3 = (const float*)d_in[6],  * cb3 = (const float*)d_in[7];
    const float* cw4 = (const float*)d_in[8],  * cb4 = (const float*)d_in[9];
    const float* cw5 = (const float*)d_in[10], * cb5 = (const float*)d_in[11];
    const float* fcw = (const float*)d_in[12], * fcb = (const float*)d_in[13];
    const float* aw1 = (const float*)d_in[14], * ab1 = (const float*)d_in[15];
    const float* aw2 = (const float*)d_in[16], * ab2 = (const float*)d_in[17];
    const float* clw = (const float*)d_in[18], * clb = (const float*)d_in[19];
    float* out = (float*)d_out;

    // workspace (bytes), non-overlapping, ~69.8 MB
    char* wsb = (char*)d_ws;
    __bf16* x1  = (__bf16*)(wsb);              // 512*4096*8   bf16 = 33,554,432 B
    __bf16* x2  = (__bf16*)(wsb + 33554432);   // 512*1024*16  bf16 = 16,777,216 B
    __bf16* x3  = (__bf16*)(wsb + 50331648);   // 512*256*32   bf16 =  8,388,608 B
    __bf16* x4  = (__bf16*)(wsb + 58720256);   // 512*64*64    bf16 =  4,194,304 B
    float*  x5  = (float*) (wsb + 62914560);   // 512*2048     f32  =  4,194,304 B
    float*  emb = (float*) (wsb + 67108864);   // 512*1024     f32  =  2,097,152 B
    float*  lg  = (float*) (wsb + 69206016);   // 512 f32
    __bf16* wt2 = (__bf16*)(wsb + 69208064);   //   3,200 bf16
    __bf16* wt3 = (__bf16*)(wsb + 69214464);   //  12,800 bf16
    __bf16* wt4 = (__bf16*)(wsb + 69240064);   //  51,200 bf16
    __bf16* wt5 = (__bf16*)(wsb + 69342464);   // 204,800 bf16

    wconv_k<8,  16 ><<<(3200   + 255) / 256, 256, 0, stream>>>(cw2, wt2);
    wconv_k<16, 32 ><<<(12800  + 255) / 256, 256, 0, stream>>>(cw3, wt3);
    wconv_k<32, 64 ><<<(51200  + 255) / 256, 256, 0, stream>>>(cw4, wt4);
    wconv_k<64, 128><<<(204800 + 255) / 256, 256, 0, stream>>>(cw5, wt5);

    conv1_k<<<512 * 4096 / 256, 256, 0, stream>>>(data, cw1, cb1, x1);

    conv_mfma_k<8,  16,  64, false><<<dim3(8192, 1), 256, 0, stream>>>(x1, wt2, cb2, x2);
    conv_mfma_k<16, 32,  32, false><<<dim3(2048, 2), 256, 0, stream>>>(x2, wt3, cb3, x3);
    conv_mfma_k<32, 64,  16, false><<<dim3(512,  4), 256, 0, stream>>>(x3, wt4, cb4, x4);
    conv_mfma_k<64, 128, 8,  true ><<<dim3(128,  8), 256, 0, stream>>>(x4, wt5, cb5, x5);

    fc_k<<<dim3(HID / 256, BATCH / 4), 256, 0, stream>>>(x5, fcw, fcb, emb);
    attention_k<<<BATCH, 128, 0, stream>>>(emb, aw1, ab1, aw2, ab2, lg);
    segment_k<<<NSEG, 256, 0, stream>>>(emb, lg, cid, clw, clb, out);
}

// Round 8
// 481.208 us; speedup vs baseline: 14.9596x; 1.2113x over previous
//
#include <hip/hip_runtime.h>
#include <hip/hip_bf16.h>
#include <math.h>

// Problem constants
#define BATCH 512
#define NSEG  64
#define HID   1024
#define ATT   128

typedef __attribute__((ext_vector_type(8))) __bf16 bf16x8;
typedef __attribute__((ext_vector_type(4))) float  f32x4;

// ---------------------------------------------------------------------------
// conv1: fp32 direct (Ci=3), fused pool+relu. Output NHWC bf16 for conv2-MFMA.
// ---------------------------------------------------------------------------
__global__ __launch_bounds__(256) void conv1_k(
    const float* __restrict__ in, const float* __restrict__ w,
    const float* __restrict__ bias, __bf16* __restrict__ out) {
    constexpr int Ci = 3, CC = 8, Hin = 128;
    constexpr int Hout = Hin / 2;
    constexpr int PIX = Hout * Hout;

    const int tid = blockIdx.x * 256 + threadIdx.x;
    const int pix = tid & (PIX - 1);
    const int b   = tid / PIX;
    const int x   = pix & (Hout - 1);
    const int y   = pix / Hout;

    const float* __restrict__ ibase = in + (size_t)b * Ci * Hin * Hin;
    const int iy0 = 2 * y - 2;
    const int ix0 = 2 * x - 2;
    const bool xL = (x >= 1);
    const bool xR = (x < Hout - 1);

    bool vy[6];
    int rb[6];
#pragma unroll
    for (int d = 0; d < 6; ++d) {
        int iy = iy0 + d;
        vy[d] = (unsigned)iy < (unsigned)Hin;
        rb[d] = vy[d] ? iy * Hin : 0;
    }

    float acc[CC * 4];
#pragma unroll
    for (int i = 0; i < CC * 4; ++i) acc[i] = 0.f;

    for (int ci = 0; ci < Ci; ++ci) {
        const float* __restrict__ ip = ibase + ci * Hin * Hin;
        float r[36];
#pragma unroll
        for (int dy = 0; dy < 6; ++dy) {
            bool vA = vy[dy] && xL;
            bool vC = vy[dy] && xR;
            float2 pA = *(const float2*)(ip + (vA ? rb[dy] + ix0 : 0));
            float2 pB = *(const float2*)(ip + rb[dy] + ix0 + 2);
            float2 pC = *(const float2*)(ip + (vC ? rb[dy] + ix0 + 4 : 0));
            r[dy * 6 + 0] = vA ? pA.x : 0.f;
            r[dy * 6 + 1] = vA ? pA.y : 0.f;
            r[dy * 6 + 2] = vy[dy] ? pB.x : 0.f;
            r[dy * 6 + 3] = vy[dy] ? pB.y : 0.f;
            r[dy * 6 + 4] = vC ? pC.x : 0.f;
            r[dy * 6 + 5] = vC ? pC.y : 0.f;
        }
#pragma unroll
        for (int cc = 0; cc < CC; ++cc) {
            const float* __restrict__ wp = w + (cc * Ci + ci) * 25;  // uniform
#pragma unroll
            for (int kh = 0; kh < 5; ++kh) {
#pragma unroll
                for (int kw = 0; kw < 5; ++kw) {
                    float wv = wp[kh * 5 + kw];
                    acc[cc * 4 + 0] = fmaf(r[kh * 6 + kw],           wv, acc[cc * 4 + 0]);
                    acc[cc * 4 + 1] = fmaf(r[kh * 6 + kw + 1],       wv, acc[cc * 4 + 1]);
                    acc[cc * 4 + 2] = fmaf(r[(kh + 1) * 6 + kw],     wv, acc[cc * 4 + 2]);
                    acc[cc * 4 + 3] = fmaf(r[(kh + 1) * 6 + kw + 1], wv, acc[cc * 4 + 3]);
                }
            }
        }
    }

    bf16x8 ov;
#pragma unroll
    for (int cc = 0; cc < CC; ++cc) {
        float m = fmaxf(fmaxf(acc[cc * 4 + 0], acc[cc * 4 + 1]),
                        fmaxf(acc[cc * 4 + 2], acc[cc * 4 + 3])) + bias[cc];
        ov[cc] = (__bf16)fmaxf(m, 0.f);
    }
    *(bf16x8*)(out + ((size_t)b * PIX + pix) * 8) = ov;
}

// ---------------------------------------------------------------------------
// Conv weight pre-convert: w[co][ci][kh][kw] fp32 -> wt[k/8][co][k%8] bf16,
// k = (kh*5+kw)*Ci + ci  (A-frag: lane m=lane&15 reads 16B = A[co][k8*8..+7]).
// ---------------------------------------------------------------------------
template<int Ci, int Co>
__global__ void wconv_k(const float* __restrict__ w, __bf16* __restrict__ wt) {
    const int n = 25 * Ci * Co;
    int t = blockIdx.x * 256 + threadIdx.x;
    if (t >= n) return;
    int j  = t & 7;
    int t2 = t >> 3;
    int co = t2 % Co;
    int k8 = t2 / Co;
    int k  = k8 * 8 + j;
    int tap = k / Ci, ci = k % Ci;
    int kh = tap / 5, kw = tap % 5;
    wt[t] = (__bf16)w[((co * Ci + ci) * 25) + kh * 5 + kw];
}

// ---------------------------------------------------------------------------
// FC weight pre-convert: fcw[o][k] fp32 (o<1024, k<2048) -> wt[k8][o][j] bf16.
// ---------------------------------------------------------------------------
__global__ void wfc_k(const float* __restrict__ w, __bf16* __restrict__ wt) {
    int t = blockIdx.x * 256 + threadIdx.x;   // n = 1024*2048 = 2,097,152
    int j  = t & 7;
    int t2 = t >> 3;
    int o  = t2 & 1023;
    int k8 = t2 >> 10;
    wt[t] = (__bf16)w[(size_t)o * 2048 + k8 * 8 + j];
}

// ---------------------------------------------------------------------------
// MFMA implicit-GEMM conv5x5(same) + bias + maxpool2 + relu.
// Hardened form verified rounds 6-7.  OUTMODE: 0 = NHWC bf16, 1 = flat bf16
// [b][co*16+oy*4+ox] (conv5 -> FC input, matches NCHW flatten order).
// ---------------------------------------------------------------------------
template<int Ci, int Co, int H, int OUTMODE>
__global__ __launch_bounds__(256) void conv_mfma_k(
    const __bf16* __restrict__ X, const __bf16* __restrict__ Wt,
    const float* __restrict__ bias, void* __restrict__ outp) {
    constexpr int W = H, NPIX = H * W, NTOT = BATCH * NPIX;
    constexpr int HALO = 2 * W + 2, SPAN = 256 + 2 * HALO, STR = Ci + 8;
    constexpr int K = 25 * Ci, KT = (K + 31) / 32;
    constexpr int LOGW = (W == 64 ? 6 : (W == 32 ? 5 : (W == 16 ? 4 : 3)));

    __shared__ __align__(16) __bf16 xs[SPAN * STR];
    __shared__ float cs[16 * 256];

    const int tid  = threadIdx.x;
    const int pos0 = blockIdx.x * 256;
    const int co0  = blockIdx.y * 16;

    // ---- stage input tile + halo (clamped at array ends; masked at use) ----
    constexpr int C8 = Ci / 8;
    for (int i = tid; i < SPAN * C8; i += 256) {
        int p   = i / C8;
        int cio = (i % C8) * 8;
        int gp  = pos0 - HALO + p;
        gp = gp < 0 ? 0 : (gp > NTOT - 1 ? NTOT - 1 : gp);
        *(bf16x8*)(xs + p * STR + cio) = *(const bf16x8*)(X + (size_t)gp * Ci + cio);
    }
    __syncthreads();

    const int lane = tid & 63, wave = tid >> 6;
    const int quad = lane >> 4, l15 = lane & 15;

    int px[4], py[4], pbase[4];
    f32x4 acc[4];
#pragma unroll
    for (int f = 0; f < 4; ++f) {
        int pl = wave * 64 + f * 16 + l15;
        int p  = pos0 + pl;
        px[f] = p & (W - 1);
        py[f] = (p >> LOGW) & (H - 1);
        pbase[f] = (pl + HALO) * STR;
        acc[f] = f32x4{0.f, 0.f, 0.f, 0.f};
    }
    const bf16x8 BZ = {};

    for (int kt = 0; kt < KT; ++kt) {
        int k8 = kt * 4 + quad;
        int kk = k8 * 8;
        bool kok = kk < K;
        int kkc  = kok ? kk : 0;
        int tap  = kkc / Ci;
        int cib  = kkc % Ci;
        int dy   = tap / 5 - 2;
        int dx   = tap % 5 - 2;
        int shift = dy * W + dx;
        bf16x8 av = *(const bf16x8*)(Wt + ((size_t)(kok ? k8 : 0) * Co + co0 + l15) * 8);
#pragma unroll
        for (int f = 0; f < 4; ++f) {
            bf16x8 bv = *(const bf16x8*)(xs + pbase[f] + shift * STR + cib);
            bool valid = kok && ((unsigned)(px[f] + dx) < (unsigned)W)
                             && ((unsigned)(py[f] + dy) < (unsigned)H);
            if (!valid) bv = BZ;
            acc[f] = __builtin_amdgcn_mfma_f32_16x16x32_bf16(av, bv, acc[f], 0, 0, 0);
        }
    }

    // ---- acc -> LDS [co16][pos256]  (C/D: col=lane&15=pos, row=quad*4+reg)
#pragma unroll
    for (int f = 0; f < 4; ++f) {
        int pl = wave * 64 + f * 16 + l15;
#pragma unroll
        for (int r = 0; r < 4; ++r) cs[(quad * 4 + r) * 256 + pl] = acc[f][r];
    }
    __syncthreads();

    // ---- pool 2x2 + bias + relu; 64 pooled outputs per tile, 4 co each ----
    {
        int opos = tid >> 2;
        int cog  = (tid & 3) * 4;
        int ocol = opos & (W / 2 - 1);
        int orow = opos >> (LOGW - 1);
        int pl0  = (orow * 2) * W + ocol * 2;
        int p    = pos0 + pl0;
        int b    = p >> (2 * LOGW);
        int yy   = (p >> LOGW) & (H - 1);
        int xx   = p & (W - 1);
        int oy = yy >> 1, ox = xx >> 1;
#pragma unroll
        for (int i = 0; i < 4; ++i) {
            int cr = cog + i;
            float v0 = cs[cr * 256 + pl0],     v1 = cs[cr * 256 + pl0 + 1];
            float v2 = cs[cr * 256 + pl0 + W], v3 = cs[cr * 256 + pl0 + W + 1];
            float m = fmaxf(fmaxf(v0, v1), fmaxf(v2, v3)) + bias[co0 + cr];
            m = fmaxf(m, 0.f);
            if (OUTMODE == 1) {
                ((__bf16*)outp)[(size_t)b * 2048 + (co0 + cr) * 16 + oy * 4 + ox] = (__bf16)m;
            } else {
                ((__bf16*)outp)[((size_t)((b * (H / 2) + oy) * (W / 2)) + ox) * Co + co0 + cr] = (__bf16)m;
            }
        }
    }
}

// ---------------------------------------------------------------------------
// FC via MFMA: emb[b][o] = sum_k Xb[b][k] * fc_w[o][k] + fc_b[o], fp32 out.
// M=16 o (blockIdx.y), N=128 b (blockIdx.x; 32 per wave as 2 frags).
// K=2048. B-frags straight from global (no intra-WG redundancy -> LDS
// staging wouldn't reduce traffic); no barriers so the K-loop pipelines.
// grid = (4, 64), 256 threads.
// ---------------------------------------------------------------------------
__global__ __launch_bounds__(256) void fc_mfma_k(
    const __bf16* __restrict__ Xb, const __bf16* __restrict__ Wfc,
    const float* __restrict__ bias, float* __restrict__ emb) {
    const int tid  = threadIdx.x;
    const int lane = tid & 63, wave = tid >> 6;
    const int quad = lane >> 4, l15 = lane & 15;
    const int n0   = blockIdx.x * 128;
    const int co0  = blockIdx.y * 16;

    int n[2];
    f32x4 acc[2];
#pragma unroll
    for (int f = 0; f < 2; ++f) {
        n[f] = n0 + wave * 32 + f * 16 + l15;
        acc[f] = f32x4{0.f, 0.f, 0.f, 0.f};
    }

#pragma unroll 4
    for (int kt = 0; kt < 64; ++kt) {
        int k8 = kt * 4 + quad;
        bf16x8 av = *(const bf16x8*)(Wfc + ((size_t)k8 * 1024 + co0 + l15) * 8);
#pragma unroll
        for (int f = 0; f < 2; ++f) {
            bf16x8 bv = *(const bf16x8*)(Xb + (size_t)n[f] * 2048 + k8 * 8);
            acc[f] = __builtin_amdgcn_mfma_f32_16x16x32_bf16(av, bv, acc[f], 0, 0, 0);
        }
    }

    // C/D: col=l15 = n, row = quad*4+r = o (4 consecutive -> f32x4 store)
    float4 b4 = *(const float4*)(bias + co0 + quad * 4);
#pragma unroll
    for (int f = 0; f < 2; ++f) {
        f32x4 v = acc[f];
        v[0] += b4.x; v[1] += b4.y; v[2] += b4.z; v[3] += b4.w;
        *(f32x4*)(emb + (size_t)n[f] * 1024 + co0 + quad * 4) = v;
    }
}

// ---------------------------------------------------------------------------
// Attention
// ---------------------------------------------------------------------------
__global__ __launch_bounds__(128) void attention_k(
    const float* __restrict__ emb, const float* __restrict__ w1,
    const float* __restrict__ b1, const float* __restrict__ w2,
    const float* __restrict__ b2, float* __restrict__ logits) {
    const int b = blockIdx.x;
    const int j = threadIdx.x;
    __shared__ float es[HID];
    for (int k = j; k < HID; k += 128) es[k] = emb[(size_t)b * HID + k];
    __syncthreads();

    float s = b1[j];
    const float* wr = w1 + (size_t)j * HID;
    for (int k = 0; k < HID; k += 4) {
        float4 wv = *(const float4*)(wr + k);
        float4 ev = *(const float4*)(es + k);
        s += wv.x * ev.x + wv.y * ev.y + wv.z * ev.z + wv.w * ev.w;
    }
    float v = tanhf(s) * w2[j];
#pragma unroll
    for (int off = 32; off > 0; off >>= 1) v += __shfl_down(v, off);
    __shared__ float wsum[2];
    if ((j & 63) == 0) wsum[j >> 6] = v;
    __syncthreads();
    if (j == 0) logits[b] = wsum[0] + wsum[1] + b2[0];
}

// ---------------------------------------------------------------------------
// Segment softmax + aggregation + classifier
// ---------------------------------------------------------------------------
__global__ __launch_bounds__(256) void segment_k(
    const float* __restrict__ emb, const float* __restrict__ logits,
    const int* __restrict__ cid, const float* __restrict__ clf_w,
    const float* __restrict__ clf_b, float* __restrict__ out) {
    const int c = blockIdx.x;
    const int t = threadIdx.x;
    __shared__ int cids[BATCH];
    __shared__ float red[256];
    for (int i = t; i < BATCH; i += 256) cids[i] = cid[i];
    __syncthreads();

    float lm = -1e30f;
    for (int b = t; b < BATCH; b += 256)
        if (cids[b] == c) lm = fmaxf(lm, logits[b]);
    red[t] = lm; __syncthreads();
    for (int s = 128; s > 0; s >>= 1) {
        if (t < s) red[t] = fmaxf(red[t], red[t + s]);
        __syncthreads();
    }
    float smax = red[0]; __syncthreads();

    float ls = 0.f;
    for (int b = t; b < BATCH; b += 256)
        if (cids[b] == c) ls += expf(logits[b] - smax);
    red[t] = ls; __syncthreads();
    for (int s = 128; s > 0; s >>= 1) {
        if (t < s) red[t] += red[t + s];
        __syncthreads();
    }
    float denom = red[0]; __syncthreads();
    float inv = (denom > 0.f) ? 1.f / denom : 0.f;

    const int h0 = t * 4;
    float g0 = 0.f, g1 = 0.f, g2 = 0.f, g3 = 0.f;
    for (int b = 0; b < BATCH; ++b) {
        if (cids[b] == c) {
            float wgt = expf(logits[b] - smax) * inv;
            float4 ev = *(const float4*)(emb + (size_t)b * HID + h0);
            g0 = fmaf(wgt, ev.x, g0);
            g1 = fmaf(wgt, ev.y, g1);
            g2 = fmaf(wgt, ev.z, g2);
            g3 = fmaf(wgt, ev.w, g3);
        }
    }
    float4 cw = *(const float4*)(clf_w + h0);
    float ca = g0 * cw.x + g1 * cw.y + g2 * cw.z + g3 * cw.w;
    red[t] = ca; __syncthreads();
    for (int s = 128; s > 0; s >>= 1) {
        if (t < s) red[t] += red[t + s];
        __syncthreads();
    }
    if (t == 0) out[c] = 1.f / (1.f + expf(-(red[0] + clf_b[0])));
}

// ---------------------------------------------------------------------------
extern "C" void kernel_launch(void* const* d_in, const int* in_sizes, int n_in,
                              void* d_out, int out_size, void* d_ws, size_t ws_size,
                              hipStream_t stream) {
    const float* data = (const float*)d_in[0];
    const int*   cid  = (const int*)d_in[1];
    const float* cw1 = (const float*)d_in[2],  * cb1 = (const float*)d_in[3];
    const float* cw2 = (const float*)d_in[4],  * cb2 = (const float*)d_in[5];
    const float* cw3 = (const float*)d_in[6],  * cb3 = (const float*)d_in[7];
    const float* cw4 = (const float*)d_in[8],  * cb4 = (const float*)d_in[9];
    const float* cw5 = (const float*)d_in[10], * cb5 = (const float*)d_in[11];
    const float* fcw = (const float*)d_in[12], * fcb = (const float*)d_in[13];
    const float* aw1 = (const float*)d_in[14], * ab1 = (const float*)d_in[15];
    const float* aw2 = (const float*)d_in[16], * ab2 = (const float*)d_in[17];
    const float* clw = (const float*)d_in[18], * clb = (const float*)d_in[19];
    float* out = (float*)d_out;

    // workspace (bytes), non-overlapping, ~71.9 MB
    char* wsb = (char*)d_ws;
    __bf16* x1  = (__bf16*)(wsb);              // 512*4096*8   bf16 = 33,554,432 B
    __bf16* x2  = (__bf16*)(wsb + 33554432);   // 512*1024*16  bf16 = 16,777,216 B
    __bf16* x3  = (__bf16*)(wsb + 50331648);   // 512*256*32   bf16 =  8,388,608 B
    __bf16* x4  = (__bf16*)(wsb + 58720256);   // 512*64*64    bf16 =  4,194,304 B
    __bf16* x5b = (__bf16*)(wsb + 62914560);   // 512*2048     bf16 =  2,097,152 B
    float*  emb = (float*) (wsb + 65011712);   // 512*1024     f32  =  2,097,152 B
    float*  lg  = (float*) (wsb + 67108864);   // 512 f32
    __bf16* wt2 = (__bf16*)(wsb + 67110912);   //   3,200 bf16
    __bf16* wt3 = (__bf16*)(wsb + 67117312);   //  12,800 bf16
    __bf16* wt4 = (__bf16*)(wsb + 67142912);   //  51,200 bf16
    __bf16* wt5 = (__bf16*)(wsb + 67245312);   // 204,800 bf16
    __bf16* wfc = (__bf16*)(wsb + 67654912);   // 2,097,152 bf16 = 4,194,304 B

    wconv_k<8,  16 ><<<(3200   + 255) / 256, 256, 0, stream>>>(cw2, wt2);
    wconv_k<16, 32 ><<<(12800  + 255) / 256, 256, 0, stream>>>(cw3, wt3);
    wconv_k<32, 64 ><<<(51200  + 255) / 256, 256, 0, stream>>>(cw4, wt4);
    wconv_k<64, 128><<<(204800 + 255) / 256, 256, 0, stream>>>(cw5, wt5);
    wfc_k<<<2097152 / 256, 256, 0, stream>>>(fcw, wfc);

    conv1_k<<<512 * 4096 / 256, 256, 0, stream>>>(data, cw1, cb1, x1);

    conv_mfma_k<8,  16,  64, 0><<<dim3(8192, 1), 256, 0, stream>>>(x1, wt2, cb2, x2);
    conv_mfma_k<16, 32,  32, 0><<<dim3(2048, 2), 256, 0, stream>>>(x2, wt3, cb3, x3);
    conv_mfma_k<32, 64,  16, 0><<<dim3(512,  4), 256, 0, stream>>>(x3, wt4, cb4, x4);
    conv_mfma_k<64, 128, 8,  1><<<dim3(128,  8), 256, 0, stream>>>(x4, wt5, cb5, x5b);

    fc_mfma_k<<<dim3(4, 64), 256, 0, stream>>>(x5b, wfc, fcb, emb);
    attention_k<<<BATCH, 128, 0, stream>>>(emb, aw1, ab1, aw2, ab2, lg);
    segment_k<<<NSEG, 256, 0, stream>>>(emb, lg, cid, clw, clb, out);
}

// Round 9
// 466.569 us; speedup vs baseline: 15.4289x; 1.0314x over previous
//
#include <hip/hip_runtime.h>
#include <hip/hip_bf16.h>
#include <math.h>

// Problem constants
#define BATCH 512
#define NSEG  64
#define HID   1024
#define ATT   128

typedef __attribute__((ext_vector_type(8))) __bf16 bf16x8;
typedef __attribute__((ext_vector_type(4))) __bf16 bf16x4;
typedef __attribute__((ext_vector_type(4))) float  f32x4;

// ---------------------------------------------------------------------------
// conv1 weight pre-convert: w[co][ci][kh][kw] (8,3,5,5) fp32 ->
// wt[k8][m16][j8] bf16 with k = tap*4 + ci (ci padded to 4), K=100 pad 128.
// Zeros at ci=3, tap>=25, m>=8  => A-side zero kills all padding in MFMA.
// ---------------------------------------------------------------------------
__global__ void wconv1_k(const float* __restrict__ w, __bf16* __restrict__ wt) {
    int t = blockIdx.x * 256 + threadIdx.x;   // n = 16*16*8 = 2048
    if (t >= 2048) return;
    int j = t & 7, m = (t >> 3) & 15, k8 = t >> 7;
    int k = k8 * 8 + j, tap = k >> 2, ci = k & 3;
    float v = 0.f;
    if (m < 8 && ci < 3 && tap < 25) v = w[(m * 3 + ci) * 25 + tap];
    wt[t] = (__bf16)v;
}

// ---------------------------------------------------------------------------
// conv1 via MFMA: fp32 NCHW input, staged to LDS as bf16 NHWC4 (conversion
// fused into staging). K=100 (25 taps x 4 ci, ci3=0), each k8 = 2 taps:
// B-frag = two b64 reads + per-half spatial mask. co 0..7 real (m 8..15
// padded zero). Fused pool+relu -> NHWC8 bf16 for conv2.
// ---------------------------------------------------------------------------
__global__ __launch_bounds__(256) void conv1_mfma_k(
    const float* __restrict__ in, const __bf16* __restrict__ Wt,
    const float* __restrict__ bias, __bf16* __restrict__ out) {
    constexpr int H = 128, W = 128, NPIX = H * W;          // 16384
    constexpr int NTOT = BATCH * NPIX;                     // 8,388,608
    constexpr int HALO = 2 * W + 2, SPAN = 256 + 2 * HALO; // 258, 772

    __shared__ __align__(16) __bf16 xs[SPAN * 4];
    __shared__ float cs[8 * 256];

    const int tid  = threadIdx.x;
    const int pos0 = blockIdx.x * 256;

    // ---- stage: NCHW fp32 -> NHWC4 bf16 (clamped; borders masked at use) --
    for (int i = tid; i < SPAN; i += 256) {
        int gp = pos0 - HALO + i;
        gp = gp < 0 ? 0 : (gp > NTOT - 1 ? NTOT - 1 : gp);
        size_t base = ((size_t)(gp >> 14) * 3) * 16384 + (gp & 16383);
        bf16x4 v = {};
        v[0] = (__bf16)in[base];
        v[1] = (__bf16)in[base + 16384];
        v[2] = (__bf16)in[base + 32768];
        *(bf16x4*)(xs + i * 4) = v;
    }
    __syncthreads();

    const int lane = tid & 63, wave = tid >> 6;
    const int quad = lane >> 4, l15 = lane & 15;

    int px[4], py[4], pbase[4];
    f32x4 acc[4];
#pragma unroll
    for (int f = 0; f < 4; ++f) {
        int pl = wave * 64 + f * 16 + l15;
        int p  = pos0 + pl;
        px[f] = p & (W - 1);
        py[f] = (p >> 7) & (H - 1);
        pbase[f] = pl + HALO;
        acc[f] = f32x4{0.f, 0.f, 0.f, 0.f};
    }

#pragma unroll
    for (int kt = 0; kt < 4; ++kt) {
        int k8 = kt * 4 + quad;
        int tap0 = k8 * 2, tap1 = tap0 + 1;
        int t0 = tap0 < 25 ? tap0 : 0;      // clamp for safe LDS addr (A=0 there)
        int t1 = tap1 < 25 ? tap1 : 0;
        int dy0 = t0 / 5 - 2, dx0 = t0 % 5 - 2;
        int dy1 = t1 / 5 - 2, dx1 = t1 % 5 - 2;
        int s0 = dy0 * W + dx0, s1 = dy1 * W + dx1;
        bf16x8 av = *(const bf16x8*)(Wt + ((size_t)k8 * 16 + l15) * 8);
#pragma unroll
        for (int f = 0; f < 4; ++f) {
            bf16x4 b0 = *(const bf16x4*)(xs + (pbase[f] + s0) * 4);
            bf16x4 b1 = *(const bf16x4*)(xs + (pbase[f] + s1) * 4);
            if (!(((unsigned)(px[f] + dx0) < (unsigned)W) &&
                  ((unsigned)(py[f] + dy0) < (unsigned)H))) b0 = (bf16x4){};
            if (!(((unsigned)(px[f] + dx1) < (unsigned)W) &&
                  ((unsigned)(py[f] + dy1) < (unsigned)H))) b1 = (bf16x4){};
            bf16x8 bv = __builtin_shufflevector(b0, b1, 0, 1, 2, 3, 4, 5, 6, 7);
            acc[f] = __builtin_amdgcn_mfma_f32_16x16x32_bf16(av, bv, acc[f], 0, 0, 0);
        }
    }

    // ---- acc -> LDS rows 0..7 (C/D: col=l15=pos, row=quad*4+r=co) ----
#pragma unroll
    for (int f = 0; f < 4; ++f) {
        int pl = wave * 64 + f * 16 + l15;
#pragma unroll
        for (int r = 0; r < 4; ++r) {
            int m = quad * 4 + r;
            if (m < 8) cs[m * 256 + pl] = acc[f][r];
        }
    }
    __syncthreads();

    // ---- pool 2x2 + bias + relu -> NHWC8 bf16; 64 opos x 8 co ----
    {
        int opos = tid >> 2;           // 0..63
        int cog  = (tid & 3) * 2;      // 0,2,4,6
        int pl0  = opos * 2;
        int p    = pos0 + pl0;
        int b    = p >> 14;
        int yy   = (p >> 7) & 127, xx = p & 127;
        int oy = yy >> 1, ox = xx >> 1;
        size_t ob = ((size_t)b * 4096 + oy * 64 + ox) * 8;
#pragma unroll
        for (int i = 0; i < 2; ++i) {
            int cr = cog + i;
            float v0 = cs[cr * 256 + pl0],       v1 = cs[cr * 256 + pl0 + 1];
            float v2 = cs[cr * 256 + pl0 + 128], v3 = cs[cr * 256 + pl0 + 129];
            float m = fmaxf(fmaxf(v0, v1), fmaxf(v2, v3)) + bias[cr];
            out[ob + cr] = (__bf16)fmaxf(m, 0.f);
        }
    }
}

// ---------------------------------------------------------------------------
// Conv weight pre-convert: w[co][ci][kh][kw] fp32 -> wt[k/8][co][k%8] bf16,
// k = (kh*5+kw)*Ci + ci  (A-frag: lane m=lane&15 reads 16B = A[co][k8*8..+7]).
// ---------------------------------------------------------------------------
template<int Ci, int Co>
__global__ void wconv_k(const float* __restrict__ w, __bf16* __restrict__ wt) {
    const int n = 25 * Ci * Co;
    int t = blockIdx.x * 256 + threadIdx.x;
    if (t >= n) return;
    int j  = t & 7;
    int t2 = t >> 3;
    int co = t2 % Co;
    int k8 = t2 / Co;
    int k  = k8 * 8 + j;
    int tap = k / Ci, ci = k % Ci;
    int kh = tap / 5, kw = tap % 5;
    wt[t] = (__bf16)w[((co * Ci + ci) * 25) + kh * 5 + kw];
}

// ---------------------------------------------------------------------------
// FC weight pre-convert: fcw[o][k] fp32 (o<1024, k<2048) -> wt[k8][o][j] bf16.
// ---------------------------------------------------------------------------
__global__ void wfc_k(const float* __restrict__ w, __bf16* __restrict__ wt) {
    int t = blockIdx.x * 256 + threadIdx.x;   // n = 1024*2048 = 2,097,152
    int j  = t & 7;
    int t2 = t >> 3;
    int o  = t2 & 1023;
    int k8 = t2 >> 10;
    wt[t] = (__bf16)w[(size_t)o * 2048 + k8 * 8 + j];
}

// ---------------------------------------------------------------------------
// MFMA implicit-GEMM conv5x5(same) + bias + maxpool2 + relu.
// Hardened form verified rounds 6-8.  OUTMODE: 0 = NHWC bf16, 1 = flat bf16
// [b][co*16+oy*4+ox] (conv5 -> FC input, matches NCHW flatten order).
// ---------------------------------------------------------------------------
template<int Ci, int Co, int H, int OUTMODE>
__global__ __launch_bounds__(256) void conv_mfma_k(
    const __bf16* __restrict__ X, const __bf16* __restrict__ Wt,
    const float* __restrict__ bias, void* __restrict__ outp) {
    constexpr int W = H, NPIX = H * W, NTOT = BATCH * NPIX;
    constexpr int HALO = 2 * W + 2, SPAN = 256 + 2 * HALO, STR = Ci + 8;
    constexpr int K = 25 * Ci, KT = (K + 31) / 32;
    constexpr int LOGW = (W == 64 ? 6 : (W == 32 ? 5 : (W == 16 ? 4 : 3)));

    __shared__ __align__(16) __bf16 xs[SPAN * STR];
    __shared__ float cs[16 * 256];

    const int tid  = threadIdx.x;
    const int pos0 = blockIdx.x * 256;
    const int co0  = blockIdx.y * 16;

    constexpr int C8 = Ci / 8;
    for (int i = tid; i < SPAN * C8; i += 256) {
        int p   = i / C8;
        int cio = (i % C8) * 8;
        int gp  = pos0 - HALO + p;
        gp = gp < 0 ? 0 : (gp > NTOT - 1 ? NTOT - 1 : gp);
        *(bf16x8*)(xs + p * STR + cio) = *(const bf16x8*)(X + (size_t)gp * Ci + cio);
    }
    __syncthreads();

    const int lane = tid & 63, wave = tid >> 6;
    const int quad = lane >> 4, l15 = lane & 15;

    int px[4], py[4], pbase[4];
    f32x4 acc[4];
#pragma unroll
    for (int f = 0; f < 4; ++f) {
        int pl = wave * 64 + f * 16 + l15;
        int p  = pos0 + pl;
        px[f] = p & (W - 1);
        py[f] = (p >> LOGW) & (H - 1);
        pbase[f] = (pl + HALO) * STR;
        acc[f] = f32x4{0.f, 0.f, 0.f, 0.f};
    }
    const bf16x8 BZ = {};

    for (int kt = 0; kt < KT; ++kt) {
        int k8 = kt * 4 + quad;
        int kk = k8 * 8;
        bool kok = kk < K;
        int kkc  = kok ? kk : 0;
        int tap  = kkc / Ci;
        int cib  = kkc % Ci;
        int dy   = tap / 5 - 2;
        int dx   = tap % 5 - 2;
        int shift = dy * W + dx;
        bf16x8 av = *(const bf16x8*)(Wt + ((size_t)(kok ? k8 : 0) * Co + co0 + l15) * 8);
#pragma unroll
        for (int f = 0; f < 4; ++f) {
            bf16x8 bv = *(const bf16x8*)(xs + pbase[f] + shift * STR + cib);
            bool valid = kok && ((unsigned)(px[f] + dx) < (unsigned)W)
                             && ((unsigned)(py[f] + dy) < (unsigned)H);
            if (!valid) bv = BZ;
            acc[f] = __builtin_amdgcn_mfma_f32_16x16x32_bf16(av, bv, acc[f], 0, 0, 0);
        }
    }

#pragma unroll
    for (int f = 0; f < 4; ++f) {
        int pl = wave * 64 + f * 16 + l15;
#pragma unroll
        for (int r = 0; r < 4; ++r) cs[(quad * 4 + r) * 256 + pl] = acc[f][r];
    }
    __syncthreads();

    {
        int opos = tid >> 2;
        int cog  = (tid & 3) * 4;
        int ocol = opos & (W / 2 - 1);
        int orow = opos >> (LOGW - 1);
        int pl0  = (orow * 2) * W + ocol * 2;
        int p    = pos0 + pl0;
        int b    = p >> (2 * LOGW);
        int yy   = (p >> LOGW) & (H - 1);
        int xx   = p & (W - 1);
        int oy = yy >> 1, ox = xx >> 1;
#pragma unroll
        for (int i = 0; i < 4; ++i) {
            int cr = cog + i;
            float v0 = cs[cr * 256 + pl0],     v1 = cs[cr * 256 + pl0 + 1];
            float v2 = cs[cr * 256 + pl0 + W], v3 = cs[cr * 256 + pl0 + W + 1];
            float m = fmaxf(fmaxf(v0, v1), fmaxf(v2, v3)) + bias[co0 + cr];
            m = fmaxf(m, 0.f);
            if (OUTMODE == 1) {
                ((__bf16*)outp)[(size_t)b * 2048 + (co0 + cr) * 16 + oy * 4 + ox] = (__bf16)m;
            } else {
                ((__bf16*)outp)[((size_t)((b * (H / 2) + oy) * (W / 2)) + ox) * Co + co0 + cr] = (__bf16)m;
            }
        }
    }
}

// ---------------------------------------------------------------------------
// FC via MFMA (verified round 8).
// ---------------------------------------------------------------------------
__global__ __launch_bounds__(256) void fc_mfma_k(
    const __bf16* __restrict__ Xb, const __bf16* __restrict__ Wfc,
    const float* __restrict__ bias, float* __restrict__ emb) {
    const int tid  = threadIdx.x;
    const int lane = tid & 63, wave = tid >> 6;
    const int quad = lane >> 4, l15 = lane & 15;
    const int n0   = blockIdx.x * 128;
    const int co0  = blockIdx.y * 16;

    int n[2];
    f32x4 acc[2];
#pragma unroll
    for (int f = 0; f < 2; ++f) {
        n[f] = n0 + wave * 32 + f * 16 + l15;
        acc[f] = f32x4{0.f, 0.f, 0.f, 0.f};
    }

#pragma unroll 4
    for (int kt = 0; kt < 64; ++kt) {
        int k8 = kt * 4 + quad;
        bf16x8 av = *(const bf16x8*)(Wfc + ((size_t)k8 * 1024 + co0 + l15) * 8);
#pragma unroll
        for (int f = 0; f < 2; ++f) {
            bf16x8 bv = *(const bf16x8*)(Xb + (size_t)n[f] * 2048 + k8 * 8);
            acc[f] = __builtin_amdgcn_mfma_f32_16x16x32_bf16(av, bv, acc[f], 0, 0, 0);
        }
    }

    float4 b4 = *(const float4*)(bias + co0 + quad * 4);
#pragma unroll
    for (int f = 0; f < 2; ++f) {
        f32x4 v = acc[f];
        v[0] += b4.x; v[1] += b4.y; v[2] += b4.z; v[3] += b4.w;
        *(f32x4*)(emb + (size_t)n[f] * 1024 + co0 + quad * 4) = v;
    }
}

// ---------------------------------------------------------------------------
// Attention
// ---------------------------------------------------------------------------
__global__ __launch_bounds__(128) void attention_k(
    const float* __restrict__ emb, const float* __restrict__ w1,
    const float* __restrict__ b1, const float* __restrict__ w2,
    const float* __restrict__ b2, float* __restrict__ logits) {
    const int b = blockIdx.x;
    const int j = threadIdx.x;
    __shared__ float es[HID];
    for (int k = j; k < HID; k += 128) es[k] = emb[(size_t)b * HID + k];
    __syncthreads();

    float s = b1[j];
    const float* wr = w1 + (size_t)j * HID;
    for (int k = 0; k < HID; k += 4) {
        float4 wv = *(const float4*)(wr + k);
        float4 ev = *(const float4*)(es + k);
        s += wv.x * ev.x + wv.y * ev.y + wv.z * ev.z + wv.w * ev.w;
    }
    float v = tanhf(s) * w2[j];
#pragma unroll
    for (int off = 32; off > 0; off >>= 1) v += __shfl_down(v, off);
    __shared__ float wsum[2];
    if ((j & 63) == 0) wsum[j >> 6] = v;
    __syncthreads();
    if (j == 0) logits[b] = wsum[0] + wsum[1] + b2[0];
}

// ---------------------------------------------------------------------------
// Segment softmax + aggregation + classifier
// ---------------------------------------------------------------------------
__global__ __launch_bounds__(256) void segment_k(
    const float* __restrict__ emb, const float* __restrict__ logits,
    const int* __restrict__ cid, const float* __restrict__ clf_w,
    const float* __restrict__ clf_b, float* __restrict__ out) {
    const int c = blockIdx.x;
    const int t = threadIdx.x;
    __shared__ int cids[BATCH];
    __shared__ float red[256];
    for (int i = t; i < BATCH; i += 256) cids[i] = cid[i];
    __syncthreads();

    float lm = -1e30f;
    for (int b = t; b < BATCH; b += 256)
        if (cids[b] == c) lm = fmaxf(lm, logits[b]);
    red[t] = lm; __syncthreads();
    for (int s = 128; s > 0; s >>= 1) {
        if (t < s) red[t] = fmaxf(red[t], red[t + s]);
        __syncthreads();
    }
    float smax = red[0]; __syncthreads();

    float ls = 0.f;
    for (int b = t; b < BATCH; b += 256)
        if (cids[b] == c) ls += expf(logits[b] - smax);
    red[t] = ls; __syncthreads();
    for (int s = 128; s > 0; s >>= 1) {
        if (t < s) red[t] += red[t + s];
        __syncthreads();
    }
    float denom = red[0]; __syncthreads();
    float inv = (denom > 0.f) ? 1.f / denom : 0.f;

    const int h0 = t * 4;
    float g0 = 0.f, g1 = 0.f, g2 = 0.f, g3 = 0.f;
    for (int b = 0; b < BATCH; ++b) {
        if (cids[b] == c) {
            float wgt = expf(logits[b] - smax) * inv;
            float4 ev = *(const float4*)(emb + (size_t)b * HID + h0);
            g0 = fmaf(wgt, ev.x, g0);
            g1 = fmaf(wgt, ev.y, g1);
            g2 = fmaf(wgt, ev.z, g2);
            g3 = fmaf(wgt, ev.w, g3);
        }
    }
    float4 cw = *(const float4*)(clf_w + h0);
    float ca = g0 * cw.x + g1 * cw.y + g2 * cw.z + g3 * cw.w;
    red[t] = ca; __syncthreads();
    for (int s = 128; s > 0; s >>= 1) {
        if (t < s) red[t] += red[t + s];
        __syncthreads();
    }
    if (t == 0) out[c] = 1.f / (1.f + expf(-(red[0] + clf_b[0])));
}

// ---------------------------------------------------------------------------
extern "C" void kernel_launch(void* const* d_in, const int* in_sizes, int n_in,
                              void* d_out, int out_size, void* d_ws, size_t ws_size,
                              hipStream_t stream) {
    const float* data = (const float*)d_in[0];
    const int*   cid  = (const int*)d_in[1];
    const float* cw1 = (const float*)d_in[2],  * cb1 = (const float*)d_in[3];
    const float* cw2 = (const float*)d_in[4],  * cb2 = (const float*)d_in[5];
    const float* cw3 = (const float*)d_in[6],  * cb3 = (const float*)d_in[7];
    const float* cw4 = (const float*)d_in[8],  * cb4 = (const float*)d_in[9];
    const float* cw5 = (const float*)d_in[10], * cb5 = (const float*)d_in[11];
    const float* fcw = (const float*)d_in[12], * fcb = (const float*)d_in[13];
    const float* aw1 = (const float*)d_in[14], * ab1 = (const float*)d_in[15];
    const float* aw2 = (const float*)d_in[16], * ab2 = (const float*)d_in[17];
    const float* clw = (const float*)d_in[18], * clb = (const float*)d_in[19];
    float* out = (float*)d_out;

    // workspace (bytes), non-overlapping, ~71.9 MB
    char* wsb = (char*)d_ws;
    __bf16* x1  = (__bf16*)(wsb);              // 512*4096*8   bf16 = 33,554,432 B
    __bf16* x2  = (__bf16*)(wsb + 33554432);   // 512*1024*16  bf16 = 16,777,216 B
    __bf16* x3  = (__bf16*)(wsb + 50331648);   // 512*256*32   bf16 =  8,388,608 B
    __bf16* x4  = (__bf16*)(wsb + 58720256);   // 512*64*64    bf16 =  4,194,304 B
    __bf16* x5b = (__bf16*)(wsb + 62914560);   // 512*2048     bf16 =  2,097,152 B
    float*  emb = (float*) (wsb + 65011712);   // 512*1024     f32  =  2,097,152 B
    float*  lg  = (float*) (wsb + 67108864);   // 512 f32
    __bf16* wt2 = (__bf16*)(wsb + 67110912);   //   3,200 bf16
    __bf16* wt3 = (__bf16*)(wsb + 67117312);   //  12,800 bf16
    __bf16* wt4 = (__bf16*)(wsb + 67142912);   //  51,200 bf16
    __bf16* wt5 = (__bf16*)(wsb + 67245312);   // 204,800 bf16
    __bf16* wfc = (__bf16*)(wsb + 67654912);   // 2,097,152 bf16 = 4,194,304 B
    __bf16* wt1 = (__bf16*)(wsb + 71849216);   //   2,048 bf16

    wconv1_k<<<8, 256, 0, stream>>>(cw1, wt1);
    wconv_k<8,  16 ><<<(3200   + 255) / 256, 256, 0, stream>>>(cw2, wt2);
    wconv_k<16, 32 ><<<(12800  + 255) / 256, 256, 0, stream>>>(cw3, wt3);
    wconv_k<32, 64 ><<<(51200  + 255) / 256, 256, 0, stream>>>(cw4, wt4);
    wconv_k<64, 128><<<(204800 + 255) / 256, 256, 0, stream>>>(cw5, wt5);
    wfc_k<<<2097152 / 256, 256, 0, stream>>>(fcw, wfc);

    conv1_mfma_k<<<32768, 256, 0, stream>>>(data, wt1, cb1, x1);

    conv_mfma_k<8,  16,  64, 0><<<dim3(8192, 1), 256, 0, stream>>>(x1, wt2, cb2, x2);
    conv_mfma_k<16, 32,  32, 0><<<dim3(2048, 2), 256, 0, stream>>>(x2, wt3, cb3, x3);
    conv_mfma_k<32, 64,  16, 0><<<dim3(512,  4), 256, 0, stream>>>(x3, wt4, cb4, x4);
    conv_mfma_k<64, 128, 8,  1><<<dim3(128,  8), 256, 0, stream>>>(x4, wt5, cb5, x5b);

    fc_mfma_k<<<dim3(4, 64), 256, 0, stream>>>(x5b, wfc, fcb, emb);
    attention_k<<<BATCH, 128, 0, stream>>>(emb, aw1, ab1, aw2, ab2, lg);
    segment_k<<<NSEG, 256, 0, stream>>>(emb, lg, cid, clw, clb, out);
}